// Round 7
// baseline (565.759 us; speedup 1.0000x reference)
//
#include <hip/hip_runtime.h>

// ---------------------------------------------------------------------------
// Attention_73813307949177
//   kx = k Wk^T + bk ; qx = q Wq^T + bq
//   score = softmax2(softmax1(qx kx^T + bias)*wei + bias)
//   out = (score kx) Wp^T + bp
// Outputs (concat): out [4096,1024] fp32, score [4096,4096] fp32
//
// R6 -> R7:
//  * REVERT mask-in-epilogue (R6 regression: 67MB serial epilogue tail,
//    score 105->130). Mask back in softmax, int4-vectorized.
//  * Tier-2 GEMMs to 4 blocks/CU: proj z*splitK2, ctx splitK4, out splitK4
//    (grid 1024 each) -- hides the ~900cyc per-k0 staging drain that makes
//    small-N GEMMs run at ~3x their compute floor at 1-2 blocks/CU.
// ---------------------------------------------------------------------------

typedef __bf16 bf16;
typedef __bf16 bf16x8 __attribute__((ext_vector_type(8)));
typedef __bf16 bf16x4 __attribute__((ext_vector_type(4)));
typedef float  f32x4  __attribute__((ext_vector_type(4)));
typedef float  f32x16 __attribute__((ext_vector_type(16)));
typedef int    i32x4  __attribute__((ext_vector_type(4)));

typedef __attribute__((address_space(1))) void as1_void;
typedef __attribute__((address_space(3))) void as3_void;

#define NQ  4096
#define NKK 4096
#define EMB 1024

#define BM 128
#define BN 128
#define BK 32

__device__ __forceinline__ void gld_lds16(const void* g, void* l) {
    __builtin_amdgcn_global_load_lds((as1_void*)g, (as3_void*)l, 16, 0, 0);
}

// ---------------------------------------------------------------------------
// prep: fp32 -> bf16 hi/lo split; 5 tensors batched via blockIdx.y
__global__ __launch_bounds__(256) void prep_all(
    const float* __restrict__ q, const float* __restrict__ k,
    const float* __restrict__ Wq, const float* __restrict__ Wk, const float* __restrict__ Wp,
    bf16* __restrict__ qh, bf16* __restrict__ ql,
    bf16* __restrict__ kh, bf16* __restrict__ kl,
    bf16* __restrict__ Wqh, bf16* __restrict__ Wql,
    bf16* __restrict__ Wkh, bf16* __restrict__ Wkl,
    bf16* __restrict__ Wph, bf16* __restrict__ Wpl,
    int nqk, int nw)
{
    const int z = blockIdx.y;
    const float* s; bf16* h; bf16* l; int n;
    switch (z) {
        case 0:  s = q;  h = qh;  l = ql;  n = nqk; break;
        case 1:  s = k;  h = kh;  l = kl;  n = nqk; break;
        case 2:  s = Wq; h = Wqh; l = Wql; n = nw;  break;
        case 3:  s = Wk; h = Wkh; l = Wkl; n = nw;  break;
        default: s = Wp; h = Wph; l = Wpl; n = nw;  break;
    }
    const int i = (blockIdx.x * 256 + threadIdx.x) * 4;
    if (i >= n) return;
    f32x4 v = *(const f32x4*)(s + i);
    bf16x4 hv, lv;
#pragma unroll
    for (int c = 0; c < 4; c++) {
        float x = v[c];
        bf16 hh = (bf16)x;
        hv[c] = hh;
        lv[c] = (bf16)(x - (float)hh);
    }
    *(bf16x4*)(h + i) = hv;
    *(bf16x4*)(l + i) = lv;
}

__global__ __launch_bounds__(256) void transpose_bf16(
    const bf16* __restrict__ src, bf16* __restrict__ dst, int R, int C)
{
    __shared__ bf16 tile[32][33];
    const int bx = blockIdx.x * 32;
    const int by = blockIdx.y * 32;
    const int tx = threadIdx.x & 31;
    const int ty = threadIdx.x >> 5;
#pragma unroll
    for (int r = 0; r < 4; r++)
        tile[ty + 8 * r][tx] = src[(size_t)(by + ty + 8 * r) * C + bx + tx];
    __syncthreads();
#pragma unroll
    for (int r = 0; r < 4; r++)
        dst[(size_t)(bx + ty + 8 * r) * R + by + tx] = tile[tx][ty + 8 * r];
}

// ---------------------------------------------------------------------------
// reduce over NS partial slices.
// MODE 0: sum->bf16(oh). MODE 1: sum+bias->f32(of). MODE 2: sum+bias->hi/lo.
template<int NS, int MODE>
__global__ __launch_bounds__(256) void reduce_k(
    const float* __restrict__ P, const float* __restrict__ bias,
    float* __restrict__ of, bf16* __restrict__ oh, bf16* __restrict__ ol,
    int n, int Nld)
{
    const int i = (blockIdx.x * 256 + threadIdx.x) * 4;
    if (i >= n) return;
    f32x4 v = *(const f32x4*)(P + i);
#pragma unroll
    for (int s = 1; s < NS; s++)
        v += *(const f32x4*)(P + (size_t)s * n + i);
    if (MODE >= 1)
        v += *(const f32x4*)(bias + (i & (Nld - 1)));
    if (MODE == 0) {
        bf16x4 o;
#pragma unroll
        for (int c = 0; c < 4; c++) o[c] = (bf16)v[c];
        *(bf16x4*)(oh + i) = o;
    } else if (MODE == 1) {
        *(f32x4*)(of + i) = v;
    } else {
        bf16x4 h, l;
#pragma unroll
        for (int c = 0; c < 4; c++) {
            bf16 hh = (bf16)v[c];
            h[c] = hh;
            l[c] = (bf16)(v[c] - (float)hh);
        }
        *(bf16x4*)(oh + i) = h;
        *(bf16x4*)(ol + i) = l;
    }
}

// ---------------------------------------------------------------------------
// Plain bf16 gemm_bt (32x32x16 core, swizzled LDS): C = A[M,K] B[N,K]^T.
// NSPLIT>0: blockIdx.z = kz -> fp32 partial slice kz.
template<int NSPLIT, int HAS_BIAS, int OUT_BF16>
__global__ __launch_bounds__(256) void gemm_bt(
    const bf16* __restrict__ A, const bf16* __restrict__ B,
    const float* __restrict__ bias,
    float* __restrict__ Cf, bf16* __restrict__ Cb,
    int M, int N, int Ksub, int lda, int ldb)
{
    __shared__ bf16 sA[BM * BK];
    __shared__ bf16 sB[BN * BK];
    const int t    = threadIdx.x;
    const int wave = t >> 6;
    const int lane = t & 63;
    const int l31  = lane & 31;
    const int lhi  = lane >> 5;
    const int wm   = wave >> 1;
    const int wn   = wave & 1;
    const int bm   = blockIdx.y * BM;
    const int bn   = blockIdx.x * BN;
    const int srow = t >> 2;
    const int gseg = (t & 3) ^ ((srow >> 1) & 3);
    const int rsw  = (l31 >> 1) & 3;
    const int kz   = (NSPLIT > 0) ? (int)blockIdx.z : 0;

    A += (size_t)kz * Ksub;
    B += (size_t)kz * Ksub;
    if (NSPLIT > 0) Cf += (size_t)kz * M * N;

    const bf16* ga = A + (size_t)(bm + srow) * lda + gseg * 8;
    const bf16* gb = B + (size_t)(bn + srow) * ldb + gseg * 8;
    char* lA = (char*)sA + wave * 1024;
    char* lB = (char*)sB + wave * 1024;

    f32x16 acc[2][2] = {};

    for (int k0 = 0; k0 < Ksub; k0 += BK) {
        __syncthreads();
        gld_lds16(ga + k0,                      lA);
        gld_lds16(ga + (size_t)64 * lda + k0,   lA + 4096);
        gld_lds16(gb + k0,                      lB);
        gld_lds16(gb + (size_t)64 * ldb + k0,   lB + 4096);
        __syncthreads();
        bf16x8 af[2][2], bfr[2][2];
#pragma unroll
        for (int mi = 0; mi < 2; mi++)
#pragma unroll
            for (int kh = 0; kh < 2; kh++)
                af[mi][kh] = *(const bf16x8*)
                    &sA[(wm * 64 + mi * 32 + l31) * BK + ((kh * 2 + lhi) ^ rsw) * 8];
#pragma unroll
        for (int nj = 0; nj < 2; nj++)
#pragma unroll
            for (int kh = 0; kh < 2; kh++)
                bfr[nj][kh] = *(const bf16x8*)
                    &sB[(wn * 64 + nj * 32 + l31) * BK + ((kh * 2 + lhi) ^ rsw) * 8];
#pragma unroll
        for (int kh = 0; kh < 2; kh++)
#pragma unroll
            for (int mi = 0; mi < 2; mi++)
#pragma unroll
                for (int nj = 0; nj < 2; nj++)
                    acc[mi][nj] = __builtin_amdgcn_mfma_f32_32x32x16_bf16(
                        af[mi][kh], bfr[nj][kh], acc[mi][nj], 0, 0, 0);
    }

#pragma unroll
    for (int mi = 0; mi < 2; mi++)
#pragma unroll
        for (int nj = 0; nj < 2; nj++) {
            const int cg = bn + wn * 64 + nj * 32 + l31;
            const float bv = HAS_BIAS ? bias[cg] : 0.0f;
#pragma unroll
            for (int r = 0; r < 16; r++) {
                const int rg = bm + wm * 64 + mi * 32 + (r & 3) + 8 * (r >> 2) + 4 * lhi;
                const float v = acc[mi][nj][r] + bv;
                const size_t idx = (size_t)rg * N + cg;
                if (NSPLIT > 0)    Cf[idx] = v;
                else if (OUT_BF16) Cb[idx] = (bf16)v;
                else               Cf[idx] = v;
            }
        }
}

// ---------------------------------------------------------------------------
// Split-precision gemm_bt (32x32x16, swizzled; AlBh + AhBl + AhBh).
// BATCH: operand set via blockIdx.z / NSPLIT. NSPLIT>0: fp32 partials to
// slice mt*NSPLIT+kz. NSPLIT==0: HILO? bf16 hi/lo (+bias) : fp32.
template<int BATCH, int NSPLIT, int HAS_BIAS, int HILO>
__global__ __launch_bounds__(256) void gemm_bt_split(
    const bf16* __restrict__ Ah0, const bf16* __restrict__ Al0,
    const bf16* __restrict__ Bh0, const bf16* __restrict__ Bl0,
    const float* __restrict__ bias0, bf16* __restrict__ Ch0, bf16* __restrict__ Cl0,
    const bf16* __restrict__ Ah1, const bf16* __restrict__ Al1,
    const bf16* __restrict__ Bh1, const bf16* __restrict__ Bl1,
    const float* __restrict__ bias1, bf16* __restrict__ Ch1, bf16* __restrict__ Cl1,
    float* __restrict__ P, float* __restrict__ Cf,
    int M, int N, int Ksub, int lda, int ldb)
{
    __shared__ bf16 sAh[BM * BK], sAl[BM * BK], sBh[BN * BK], sBl[BN * BK];
    const int t    = threadIdx.x;
    const int wave = t >> 6;
    const int lane = t & 63;
    const int l31  = lane & 31;
    const int lhi  = lane >> 5;
    const int wm   = wave >> 1;
    const int wn   = wave & 1;
    const int bm   = blockIdx.y * BM;
    const int bn   = blockIdx.x * BN;
    const int srow = t >> 2;
    const int gseg = (t & 3) ^ ((srow >> 1) & 3);
    const int rsw  = (l31 >> 1) & 3;

    const int zs = (NSPLIT > 0) ? NSPLIT : 1;
    const int mt = BATCH ? ((int)blockIdx.z / zs) : 0;
    const int kz = (NSPLIT > 0) ? ((int)blockIdx.z % zs) : 0;

    const bf16* Ah = (BATCH && mt) ? Ah1 : Ah0;
    const bf16* Al = (BATCH && mt) ? Al1 : Al0;
    const bf16* Bh = (BATCH && mt) ? Bh1 : Bh0;
    const bf16* Bl = (BATCH && mt) ? Bl1 : Bl0;
    const float* bias = (BATCH && mt) ? bias1 : bias0;
    bf16* Ch = (BATCH && mt) ? Ch1 : Ch0;
    bf16* Cl = (BATCH && mt) ? Cl1 : Cl0;
    if (NSPLIT > 0) P += (size_t)(mt * zs + kz) * M * N;

    const size_t offA = (size_t)(bm + srow) * lda + gseg * 8 + (size_t)kz * Ksub;
    const size_t offB = (size_t)(bn + srow) * ldb + gseg * 8 + (size_t)kz * Ksub;
    char* lAh = (char*)sAh + wave * 1024;
    char* lAl = (char*)sAl + wave * 1024;
    char* lBh = (char*)sBh + wave * 1024;
    char* lBl = (char*)sBl + wave * 1024;

    f32x16 acc[2][2] = {};

    for (int k0 = 0; k0 < Ksub; k0 += BK) {
        __syncthreads();
        gld_lds16(Ah + offA + k0,                    lAh);
        gld_lds16(Ah + offA + (size_t)64 * lda + k0, lAh + 4096);
        gld_lds16(Al + offA + k0,                    lAl);
        gld_lds16(Al + offA + (size_t)64 * lda + k0, lAl + 4096);
        gld_lds16(Bh + offB + k0,                    lBh);
        gld_lds16(Bh + offB + (size_t)64 * ldb + k0, lBh + 4096);
        gld_lds16(Bl + offB + k0,                    lBl);
        gld_lds16(Bl + offB + (size_t)64 * ldb + k0, lBl + 4096);
        __syncthreads();
#pragma unroll
        for (int kh = 0; kh < 2; kh++) {
            const int ksw = ((kh * 2 + lhi) ^ rsw) * 8;
            bf16x8 ah[2], al[2], bh2[2], bl2[2];
#pragma unroll
            for (int mi = 0; mi < 2; mi++) {
                const int ro = (wm * 64 + mi * 32 + l31) * BK + ksw;
                ah[mi] = *(const bf16x8*)&sAh[ro];
                al[mi] = *(const bf16x8*)&sAl[ro];
            }
#pragma unroll
            for (int nj = 0; nj < 2; nj++) {
                const int ro = (wn * 64 + nj * 32 + l31) * BK + ksw;
                bh2[nj] = *(const bf16x8*)&sBh[ro];
                bl2[nj] = *(const bf16x8*)&sBl[ro];
            }
#pragma unroll
            for (int mi = 0; mi < 2; mi++)
#pragma unroll
                for (int nj = 0; nj < 2; nj++) {
                    acc[mi][nj] = __builtin_amdgcn_mfma_f32_32x32x16_bf16(al[mi], bh2[nj], acc[mi][nj], 0, 0, 0);
                    acc[mi][nj] = __builtin_amdgcn_mfma_f32_32x32x16_bf16(ah[mi], bl2[nj], acc[mi][nj], 0, 0, 0);
                    acc[mi][nj] = __builtin_amdgcn_mfma_f32_32x32x16_bf16(ah[mi], bh2[nj], acc[mi][nj], 0, 0, 0);
                }
        }
    }

#pragma unroll
    for (int mi = 0; mi < 2; mi++)
#pragma unroll
        for (int nj = 0; nj < 2; nj++) {
            const int cg = bn + wn * 64 + nj * 32 + l31;
            const float bv = (NSPLIT == 0 && HAS_BIAS) ? bias[cg] : 0.0f;
#pragma unroll
            for (int r = 0; r < 16; r++) {
                const int rg = bm + wm * 64 + mi * 32 + (r & 3) + 8 * (r >> 2) + 4 * lhi;
                const float v = acc[mi][nj][r] + bv;
                const size_t idx = (size_t)rg * N + cg;
                if (NSPLIT > 0) {
                    P[idx] = v;
                } else if (HILO) {
                    const bf16 hh = (bf16)v;
                    Ch[idx] = hh;
                    Cl[idx] = (bf16)(v - (float)hh);
                } else {
                    Cf[idx] = v;
                }
            }
        }
}

// ---------------------------------------------------------------------------
// Score GEMM: split precision, 4x2 wave tile (wave = 128x64), block 128x256.
// (R5 form -- no mask in epilogue; that was R6's regression.)
__global__ __launch_bounds__(256, 2) void gemm_score(
    const bf16* __restrict__ Ah, const bf16* __restrict__ Al,
    const bf16* __restrict__ Bh, const bf16* __restrict__ Bl,
    float* __restrict__ Cf, int N, int K)
{
    __shared__ bf16 sAh[128 * BK], sAl[128 * BK], sBh[256 * BK], sBl[256 * BK];
    const int t    = threadIdx.x;
    const int wave = t >> 6;
    const int lane = t & 63;
    const int l31  = lane & 31;
    const int lhi  = lane >> 5;
    const int bm   = blockIdx.y * 128;
    const int bn   = blockIdx.x * 256;
    const int srow = t >> 2;
    const int gseg = (t & 3) ^ ((srow >> 1) & 3);
    const int rsw  = (l31 >> 1) & 3;

    const size_t offA = (size_t)(bm + srow) * K + gseg * 8;
    const size_t offB = (size_t)(bn + srow) * K + gseg * 8;
    char* lAh = (char*)sAh + wave * 1024;
    char* lAl = (char*)sAl + wave * 1024;
    char* lBh = (char*)sBh + wave * 1024;
    char* lBl = (char*)sBl + wave * 1024;

    f32x16 acc[4][2] = {};

    for (int k0 = 0; k0 < K; k0 += BK) {
        __syncthreads();
        gld_lds16(Ah + offA + k0,                  lAh);
        gld_lds16(Ah + offA + (size_t)64 * K + k0, lAh + 4096);
        gld_lds16(Al + offA + k0,                  lAl);
        gld_lds16(Al + offA + (size_t)64 * K + k0, lAl + 4096);
#pragma unroll
        for (int rb = 0; rb < 4; rb++) {
            gld_lds16(Bh + offB + (size_t)(64 * rb) * K + k0, lBh + rb * 4096);
            gld_lds16(Bl + offB + (size_t)(64 * rb) * K + k0, lBl + rb * 4096);
        }
        __syncthreads();
#pragma unroll
        for (int kh = 0; kh < 2; kh++) {
            const int ksw = ((kh * 2 + lhi) ^ rsw) * 8;
            bf16x8 ah[4], al[4], bh2[2], bl2[2];
#pragma unroll
            for (int mi = 0; mi < 4; mi++) {
                const int ro = (mi * 32 + l31) * BK + ksw;
                ah[mi] = *(const bf16x8*)&sAh[ro];
                al[mi] = *(const bf16x8*)&sAl[ro];
            }
#pragma unroll
            for (int nj = 0; nj < 2; nj++) {
                const int ro = (wave * 64 + nj * 32 + l31) * BK + ksw;
                bh2[nj] = *(const bf16x8*)&sBh[ro];
                bl2[nj] = *(const bf16x8*)&sBl[ro];
            }
#pragma unroll
            for (int mi = 0; mi < 4; mi++)
#pragma unroll
                for (int nj = 0; nj < 2; nj++) {
                    acc[mi][nj] = __builtin_amdgcn_mfma_f32_32x32x16_bf16(al[mi], bh2[nj], acc[mi][nj], 0, 0, 0);
                    acc[mi][nj] = __builtin_amdgcn_mfma_f32_32x32x16_bf16(ah[mi], bl2[nj], acc[mi][nj], 0, 0, 0);
                    acc[mi][nj] = __builtin_amdgcn_mfma_f32_32x32x16_bf16(ah[mi], bh2[nj], acc[mi][nj], 0, 0, 0);
                }
        }
    }

#pragma unroll
    for (int mi = 0; mi < 4; mi++)
#pragma unroll
        for (int nj = 0; nj < 2; nj++) {
            const int cg = bn + wave * 64 + nj * 32 + l31;
#pragma unroll
            for (int r = 0; r < 16; r++) {
                const int rg = bm + mi * 32 + (r & 3) + 8 * (r >> 2) + 4 * lhi;
                Cf[(size_t)rg * N + cg] = acc[mi][nj][r];
            }
        }
}

// ---------------------------------------------------------------------------
__device__ __forceinline__ float wred_max(float v) {
#pragma unroll
    for (int off = 32; off > 0; off >>= 1) v = fmaxf(v, __shfl_xor(v, off));
    return v;
}
__device__ __forceinline__ float wred_sum(float v) {
#pragma unroll
    for (int off = 32; off > 0; off >>= 1) v += __shfl_xor(v, off);
    return v;
}

// Fused double softmax, fully vectorized (16 contiguous cols/thread;
// f32x4 score/wei, i32x4 mask, bf16x8 stores).
__global__ __launch_bounds__(256) void softmax2_kernel(
    float* __restrict__ score, const int* __restrict__ mask,
    const float* __restrict__ wei, bf16* __restrict__ scoreb)
{
    __shared__ float sred[4];
    const int row = blockIdx.x;
    const int t   = threadIdx.x;
    const size_t base = (size_t)row * NKK + (size_t)t * 16;
    const int wv = t >> 6, ln = t & 63;

    float l[16], w[16];
    unsigned mb = 0;
#pragma unroll
    for (int c = 0; c < 4; c++) {
        *(f32x4*)(l + 4 * c) = *(const f32x4*)(score + base + 4 * c);
        *(f32x4*)(w + 4 * c) = *(const f32x4*)(wei + base + 4 * c);
        i32x4 mv = *(const i32x4*)(mask + base + 4 * c);
#pragma unroll
        for (int j = 0; j < 4; j++) if (mv[j] != 0) mb |= 1u << (4 * c + j);
    }

    // pass 1
    float mx = -__builtin_inff();
#pragma unroll
    for (int s = 0; s < 16; s++) if (mb & (1u << s)) mx = fmaxf(mx, l[s]);
    mx = wred_max(mx);
    if (ln == 0) sred[wv] = mx;
    __syncthreads();
    mx = fmaxf(fmaxf(sred[0], sred[1]), fmaxf(sred[2], sred[3]));
    __syncthreads();
    float sum = 0.f;
#pragma unroll
    for (int s = 0; s < 16; s++) {
        const float e = (mb & (1u << s)) ? __expf(l[s] - mx) : 0.f;
        l[s] = e; sum += e;
    }
    sum = wred_sum(sum);
    if (ln == 0) sred[wv] = sum;
    __syncthreads();
    sum = sred[0] + sred[1] + sred[2] + sred[3];
    __syncthreads();
    const float inv1 = 1.0f / sum;

#pragma unroll
    for (int s = 0; s < 16; s++) l[s] = l[s] * inv1 * w[s];

    // pass 2
    float mx2 = -__builtin_inff();
#pragma unroll
    for (int s = 0; s < 16; s++) if (mb & (1u << s)) mx2 = fmaxf(mx2, l[s]);
    mx2 = wred_max(mx2);
    if (ln == 0) sred[wv] = mx2;
    __syncthreads();
    mx2 = fmaxf(fmaxf(sred[0], sred[1]), fmaxf(sred[2], sred[3]));
    __syncthreads();
    float sum2 = 0.f;
#pragma unroll
    for (int s = 0; s < 16; s++) {
        const float e = (mb & (1u << s)) ? __expf(l[s] - mx2) : 0.f;
        l[s] = e; sum2 += e;
    }
    sum2 = wred_sum(sum2);
    if (ln == 0) sred[wv] = sum2;
    __syncthreads();
    sum2 = sred[0] + sred[1] + sred[2] + sred[3];
    const float inv2 = 1.0f / sum2;

#pragma unroll
    for (int c = 0; c < 4; c++) {
        f32x4 pv;
#pragma unroll
        for (int j = 0; j < 4; j++) pv[j] = l[4 * c + j] * inv2;
        *(f32x4*)(score + base + 4 * c) = pv;
#pragma unroll
        for (int j = 0; j < 4; j++) l[4 * c + j] = pv[j];
    }
    bf16x8 b0, b1;
#pragma unroll
    for (int j = 0; j < 8; j++) { b0[j] = (bf16)l[j]; b1[j] = (bf16)l[8 + j]; }
    *(bf16x8*)(scoreb + base)     = b0;
    *(bf16x8*)(scoreb + base + 8) = b1;
}

// ---------------------------------------------------------------------------
extern "C" void kernel_launch(void* const* d_in, const int* in_sizes, int n_in,
                              void* d_out, int out_size, void* d_ws, size_t ws_size,
                              hipStream_t stream)
{
    (void)in_sizes; (void)n_in; (void)out_size;
    const float* q    = (const float*)d_in[0];
    const float* k    = (const float*)d_in[1];
    const int*   mask = (const int*)  d_in[2];
    const float* wei  = (const float*)d_in[3];
    const float* Wq   = (const float*)d_in[4];
    const float* bq   = (const float*)d_in[5];
    const float* Wk   = (const float*)d_in[6];
    const float* bk   = (const float*)d_in[7];
    const float* Wp   = (const float*)d_in[8];
    const float* bp   = (const float*)d_in[9];

    float* out   = (float*)d_out;
    float* score = (float*)d_out + (size_t)NQ * EMB;

    char* ws = (char*)d_ws;
    size_t off = 0;
    auto alloc = [&](size_t bytes) -> char* {
        char* p = ws + off; off += (bytes + 255) & ~(size_t)255; return p;
    };
    const size_t n_qk = (size_t)NQ * EMB;
    const size_t n_w  = (size_t)EMB * EMB;
    const size_t n_sc = (size_t)NQ * NKK;

    bf16* qh   = (bf16*)alloc(n_qk * 2);
    bf16* ql   = (bf16*)alloc(n_qk * 2);
    bf16* kh   = (bf16*)alloc(n_qk * 2);
    bf16* kl   = (bf16*)alloc(n_qk * 2);
    bf16* qxh  = (bf16*)alloc(n_qk * 2);
    bf16* qxl  = (bf16*)alloc(n_qk * 2);
    bf16* kxh  = (bf16*)alloc(n_qk * 2);
    bf16* kxl  = (bf16*)alloc(n_qk * 2);
    bf16* Wqh  = (bf16*)alloc(n_w * 2);
    bf16* Wql  = (bf16*)alloc(n_w * 2);
    bf16* Wkh  = (bf16*)alloc(n_w * 2);
    bf16* Wkl  = (bf16*)alloc(n_w * 2);
    bf16* Wpb  = (bf16*)alloc(n_w * 2);
    bf16* Wpl  = (bf16*)alloc(n_w * 2);
    bf16* kxTb = (bf16*)alloc(n_qk * 2);
    bf16* ctxb = (bf16*)alloc(n_qk * 2);
    bf16* scoreb = (bf16*)alloc(n_sc * 2);
    const size_t base_off = off;
    float* P = (float*)alloc(4 * n_qk * 4);   // 67 MB partials (4 slices)
    const bool ws_ok = (off <= ws_size);
    if (base_off > ws_size) return;

    const int MN = (int)n_qk;

    // 1) prep: all 5 hi/lo splits in one launch
    prep_all<<<dim3(n_qk / 1024, 5), 256, 0, stream>>>(
        q, k, Wq, Wk, Wp,
        qh, ql, kh, kl, Wqh, Wql, Wkh, Wkl, Wpb, Wpl,
        (int)n_qk, (int)n_w);

    // 2) projections: z-batch x split-K2 -> 1024 blocks (4/CU)
    if (ws_ok) {
        gemm_bt_split<1, 2, 0, 0><<<dim3(EMB / BN, NQ / BM, 4), 256, 0, stream>>>(
            qh, ql, Wqh, Wql, nullptr, nullptr, nullptr,
            kh, kl, Wkh, Wkl, nullptr, nullptr, nullptr,
            P, nullptr, NQ, EMB, EMB / 2, EMB, EMB);
        reduce_k<2, 2><<<dim3(MN / 1024), 256, 0, stream>>>(
            P,              bq, nullptr, qxh, qxl, MN, EMB);
        reduce_k<2, 2><<<dim3(MN / 1024), 256, 0, stream>>>(
            P + 2 * n_qk,   bk, nullptr, kxh, kxl, MN, EMB);
    } else {
        gemm_bt_split<1, 0, 1, 1><<<dim3(EMB / BN, NQ / BM, 2), 256, 0, stream>>>(
            qh, ql, Wqh, Wql, bq, qxh, qxl,
            kh, kl, Wkh, Wkl, bk, kxh, kxl,
            nullptr, nullptr, NQ, EMB, EMB, EMB, EMB);
    }

    // 3) kx^T for ctx GEMM B-operand
    transpose_bf16<<<dim3(EMB / 32, NKK / 32), 256, 0, stream>>>(kxh, kxTb, NKK, EMB);

    // 4) score logits = qx kx^T (4x2-tile split kernel, fp32 into d_out)
    gemm_score<<<dim3(NKK / 256, NQ / 128), 256, 0, stream>>>(
        qxh, qxl, kxh, kxl, score, NKK, EMB);

    // 5) fused double softmax (vectorized, mask int4)
    softmax2_kernel<<<dim3(NQ), 256, 0, stream>>>(score, mask, wei, scoreb);

    // 6) ctx = p2 @ kx  (split-K=4 -> 1024 blocks)
    if (ws_ok) {
        gemm_bt<4, 0, 0><<<dim3(EMB / BN, NQ / BM, 4), 256, 0, stream>>>(
            scoreb, kxTb, nullptr, P, nullptr, NQ, EMB, NKK / 4, NKK, NKK);
        reduce_k<4, 0><<<dim3(MN / 1024), 256, 0, stream>>>(
            P, nullptr, nullptr, ctxb, nullptr, MN, EMB);
    } else {
        gemm_bt<0, 0, 1><<<dim3(EMB / BN, NQ / BM), 256, 0, stream>>>(
            scoreb, kxTb, nullptr, nullptr, ctxb, NQ, EMB, NKK, NKK, NKK);
    }

    // 7) out = ctx @ Wp^T + bp  (split-K=4 -> 1024 blocks)
    if (ws_ok) {
        gemm_bt<4, 0, 0><<<dim3(EMB / BN, NQ / BM, 4), 256, 0, stream>>>(
            ctxb, Wpb, nullptr, P, nullptr, NQ, EMB, EMB / 4, EMB, EMB);
        reduce_k<4, 1><<<dim3(MN / 1024), 256, 0, stream>>>(
            P, bp, out, nullptr, nullptr, MN, EMB);
    } else {
        gemm_bt<0, 1, 0><<<dim3(EMB / BN, NQ / BM), 256, 0, stream>>>(
            ctxb, Wpb, bp, out, nullptr, NQ, EMB, EMB, EMB, EMB);
    }
}

// Round 8
// 512.497 us; speedup vs baseline: 1.1039x; 1.1039x over previous
//
#include <hip/hip_runtime.h>

// ---------------------------------------------------------------------------
// Attention_73813307949177
//   kx = k Wk^T + bk ; qx = q Wq^T + bq
//   score = softmax2(softmax1(qx kx^T + bias)*wei + bias)
//   out = (score kx) Wp^T + bp
// Outputs (concat): out [4096,1024] fp32, score [4096,4096] fp32
//
// R7 -> R8: revert tier-2 to the R5 measured optimum (proj z-batch direct,
// ctx/out split-K2). R7's split-K escalation cost +62us in partial traffic
// (+134MB proj round-trip) + 4 dispatches. Keep R6/R7 wins: merged prep_all,
// vectorized softmax (f32x4/i32x4/bf16x8). New: nontemporal store for p2
// fp32 (never re-read; ctx consumes the bf16 copy).
// ---------------------------------------------------------------------------

typedef __bf16 bf16;
typedef __bf16 bf16x8 __attribute__((ext_vector_type(8)));
typedef __bf16 bf16x4 __attribute__((ext_vector_type(4)));
typedef float  f32x4  __attribute__((ext_vector_type(4)));
typedef float  f32x16 __attribute__((ext_vector_type(16)));
typedef int    i32x4  __attribute__((ext_vector_type(4)));

typedef __attribute__((address_space(1))) void as1_void;
typedef __attribute__((address_space(3))) void as3_void;

#define NQ  4096
#define NKK 4096
#define EMB 1024

#define BM 128
#define BN 128
#define BK 32

__device__ __forceinline__ void gld_lds16(const void* g, void* l) {
    __builtin_amdgcn_global_load_lds((as1_void*)g, (as3_void*)l, 16, 0, 0);
}

// ---------------------------------------------------------------------------
// prep: fp32 -> bf16 hi/lo split; 5 tensors batched via blockIdx.y
__global__ __launch_bounds__(256) void prep_all(
    const float* __restrict__ q, const float* __restrict__ k,
    const float* __restrict__ Wq, const float* __restrict__ Wk, const float* __restrict__ Wp,
    bf16* __restrict__ qh, bf16* __restrict__ ql,
    bf16* __restrict__ kh, bf16* __restrict__ kl,
    bf16* __restrict__ Wqh, bf16* __restrict__ Wql,
    bf16* __restrict__ Wkh, bf16* __restrict__ Wkl,
    bf16* __restrict__ Wph, bf16* __restrict__ Wpl,
    int nqk, int nw)
{
    const int z = blockIdx.y;
    const float* s; bf16* h; bf16* l; int n;
    switch (z) {
        case 0:  s = q;  h = qh;  l = ql;  n = nqk; break;
        case 1:  s = k;  h = kh;  l = kl;  n = nqk; break;
        case 2:  s = Wq; h = Wqh; l = Wql; n = nw;  break;
        case 3:  s = Wk; h = Wkh; l = Wkl; n = nw;  break;
        default: s = Wp; h = Wph; l = Wpl; n = nw;  break;
    }
    const int i = (blockIdx.x * 256 + threadIdx.x) * 4;
    if (i >= n) return;
    f32x4 v = *(const f32x4*)(s + i);
    bf16x4 hv, lv;
#pragma unroll
    for (int c = 0; c < 4; c++) {
        float x = v[c];
        bf16 hh = (bf16)x;
        hv[c] = hh;
        lv[c] = (bf16)(x - (float)hh);
    }
    *(bf16x4*)(h + i) = hv;
    *(bf16x4*)(l + i) = lv;
}

__global__ __launch_bounds__(256) void transpose_bf16(
    const bf16* __restrict__ src, bf16* __restrict__ dst, int R, int C)
{
    __shared__ bf16 tile[32][33];
    const int bx = blockIdx.x * 32;
    const int by = blockIdx.y * 32;
    const int tx = threadIdx.x & 31;
    const int ty = threadIdx.x >> 5;
#pragma unroll
    for (int r = 0; r < 4; r++)
        tile[ty + 8 * r][tx] = src[(size_t)(by + ty + 8 * r) * C + bx + tx];
    __syncthreads();
#pragma unroll
    for (int r = 0; r < 4; r++)
        dst[(size_t)(bx + ty + 8 * r) * R + by + tx] = tile[tx][ty + 8 * r];
}

// ---------------------------------------------------------------------------
// reduce over NS partial slices. MODE 0: sum->bf16. MODE 1: sum+bias->f32.
template<int NS, int MODE>
__global__ __launch_bounds__(256) void reduce_k(
    const float* __restrict__ P, const float* __restrict__ bias,
    float* __restrict__ of, bf16* __restrict__ oh, int n, int Nld)
{
    const int i = (blockIdx.x * 256 + threadIdx.x) * 4;
    if (i >= n) return;
    f32x4 v = *(const f32x4*)(P + i);
#pragma unroll
    for (int s = 1; s < NS; s++)
        v += *(const f32x4*)(P + (size_t)s * n + i);
    if (MODE == 1)
        v += *(const f32x4*)(bias + (i & (Nld - 1)));
    if (MODE == 0) {
        bf16x4 o;
#pragma unroll
        for (int c = 0; c < 4; c++) o[c] = (bf16)v[c];
        *(bf16x4*)(oh + i) = o;
    } else {
        *(f32x4*)(of + i) = v;
    }
}

// ---------------------------------------------------------------------------
// Plain bf16 gemm_bt (32x32x16 core, swizzled LDS): C = A[M,K] B[N,K]^T.
// NSPLIT>0: blockIdx.z = kz -> fp32 partial slice kz.
template<int NSPLIT, int HAS_BIAS, int OUT_BF16>
__global__ __launch_bounds__(256) void gemm_bt(
    const bf16* __restrict__ A, const bf16* __restrict__ B,
    const float* __restrict__ bias,
    float* __restrict__ Cf, bf16* __restrict__ Cb,
    int M, int N, int Ksub, int lda, int ldb)
{
    __shared__ bf16 sA[BM * BK];
    __shared__ bf16 sB[BN * BK];
    const int t    = threadIdx.x;
    const int wave = t >> 6;
    const int lane = t & 63;
    const int l31  = lane & 31;
    const int lhi  = lane >> 5;
    const int wm   = wave >> 1;
    const int wn   = wave & 1;
    const int bm   = blockIdx.y * BM;
    const int bn   = blockIdx.x * BN;
    const int srow = t >> 2;
    const int gseg = (t & 3) ^ ((srow >> 1) & 3);
    const int rsw  = (l31 >> 1) & 3;
    const int kz   = (NSPLIT > 0) ? (int)blockIdx.z : 0;

    A += (size_t)kz * Ksub;
    B += (size_t)kz * Ksub;
    if (NSPLIT > 0) Cf += (size_t)kz * M * N;

    const bf16* ga = A + (size_t)(bm + srow) * lda + gseg * 8;
    const bf16* gb = B + (size_t)(bn + srow) * ldb + gseg * 8;
    char* lA = (char*)sA + wave * 1024;
    char* lB = (char*)sB + wave * 1024;

    f32x16 acc[2][2] = {};

    for (int k0 = 0; k0 < Ksub; k0 += BK) {
        __syncthreads();
        gld_lds16(ga + k0,                      lA);
        gld_lds16(ga + (size_t)64 * lda + k0,   lA + 4096);
        gld_lds16(gb + k0,                      lB);
        gld_lds16(gb + (size_t)64 * ldb + k0,   lB + 4096);
        __syncthreads();
        bf16x8 af[2][2], bfr[2][2];
#pragma unroll
        for (int mi = 0; mi < 2; mi++)
#pragma unroll
            for (int kh = 0; kh < 2; kh++)
                af[mi][kh] = *(const bf16x8*)
                    &sA[(wm * 64 + mi * 32 + l31) * BK + ((kh * 2 + lhi) ^ rsw) * 8];
#pragma unroll
        for (int nj = 0; nj < 2; nj++)
#pragma unroll
            for (int kh = 0; kh < 2; kh++)
                bfr[nj][kh] = *(const bf16x8*)
                    &sB[(wn * 64 + nj * 32 + l31) * BK + ((kh * 2 + lhi) ^ rsw) * 8];
#pragma unroll
        for (int kh = 0; kh < 2; kh++)
#pragma unroll
            for (int mi = 0; mi < 2; mi++)
#pragma unroll
                for (int nj = 0; nj < 2; nj++)
                    acc[mi][nj] = __builtin_amdgcn_mfma_f32_32x32x16_bf16(
                        af[mi][kh], bfr[nj][kh], acc[mi][nj], 0, 0, 0);
    }

#pragma unroll
    for (int mi = 0; mi < 2; mi++)
#pragma unroll
        for (int nj = 0; nj < 2; nj++) {
            const int cg = bn + wn * 64 + nj * 32 + l31;
            const float bv = HAS_BIAS ? bias[cg] : 0.0f;
#pragma unroll
            for (int r = 0; r < 16; r++) {
                const int rg = bm + wm * 64 + mi * 32 + (r & 3) + 8 * (r >> 2) + 4 * lhi;
                const float v = acc[mi][nj][r] + bv;
                const size_t idx = (size_t)rg * N + cg;
                if (NSPLIT > 0)    Cf[idx] = v;
                else if (OUT_BF16) Cb[idx] = (bf16)v;
                else               Cf[idx] = v;
            }
        }
}

// ---------------------------------------------------------------------------
// Split-precision gemm_bt (32x32x16, 2x2 wave tile; AlBh + AhBl + AhBh).
// Projections: BATCH via blockIdx.z, direct bias + hi/lo epilogue.
template<int BATCH, int HAS_BIAS, int HILO>
__global__ __launch_bounds__(256) void gemm_bt_split(
    const bf16* __restrict__ Ah0, const bf16* __restrict__ Al0,
    const bf16* __restrict__ Bh0, const bf16* __restrict__ Bl0,
    const float* __restrict__ bias0, bf16* __restrict__ Ch0, bf16* __restrict__ Cl0,
    const bf16* __restrict__ Ah1, const bf16* __restrict__ Al1,
    const bf16* __restrict__ Bh1, const bf16* __restrict__ Bl1,
    const float* __restrict__ bias1, bf16* __restrict__ Ch1, bf16* __restrict__ Cl1,
    float* __restrict__ Cf,
    int M, int N, int K)
{
    __shared__ bf16 sAh[BM * BK], sAl[BM * BK], sBh[BN * BK], sBl[BN * BK];
    const int t    = threadIdx.x;
    const int wave = t >> 6;
    const int lane = t & 63;
    const int l31  = lane & 31;
    const int lhi  = lane >> 5;
    const int wm   = wave >> 1;
    const int wn   = wave & 1;
    const int bm   = blockIdx.y * BM;
    const int bn   = blockIdx.x * BN;
    const int srow = t >> 2;
    const int gseg = (t & 3) ^ ((srow >> 1) & 3);
    const int rsw  = (l31 >> 1) & 3;

    const int mt = BATCH ? (int)blockIdx.z : 0;

    const bf16* Ah = (BATCH && mt) ? Ah1 : Ah0;
    const bf16* Al = (BATCH && mt) ? Al1 : Al0;
    const bf16* Bh = (BATCH && mt) ? Bh1 : Bh0;
    const bf16* Bl = (BATCH && mt) ? Bl1 : Bl0;
    const float* bias = (BATCH && mt) ? bias1 : bias0;
    bf16* Ch = (BATCH && mt) ? Ch1 : Ch0;
    bf16* Cl = (BATCH && mt) ? Cl1 : Cl0;

    const size_t offA = (size_t)(bm + srow) * K + gseg * 8;
    const size_t offB = (size_t)(bn + srow) * K + gseg * 8;
    char* lAh = (char*)sAh + wave * 1024;
    char* lAl = (char*)sAl + wave * 1024;
    char* lBh = (char*)sBh + wave * 1024;
    char* lBl = (char*)sBl + wave * 1024;

    f32x16 acc[2][2] = {};

    for (int k0 = 0; k0 < K; k0 += BK) {
        __syncthreads();
        gld_lds16(Ah + offA + k0,                  lAh);
        gld_lds16(Ah + offA + (size_t)64 * K + k0, lAh + 4096);
        gld_lds16(Al + offA + k0,                  lAl);
        gld_lds16(Al + offA + (size_t)64 * K + k0, lAl + 4096);
        gld_lds16(Bh + offB + k0,                  lBh);
        gld_lds16(Bh + offB + (size_t)64 * K + k0, lBh + 4096);
        gld_lds16(Bl + offB + k0,                  lBl);
        gld_lds16(Bl + offB + (size_t)64 * K + k0, lBl + 4096);
        __syncthreads();
#pragma unroll
        for (int kh = 0; kh < 2; kh++) {
            const int ksw = ((kh * 2 + lhi) ^ rsw) * 8;
            bf16x8 ah[2], al[2], bh2[2], bl2[2];
#pragma unroll
            for (int mi = 0; mi < 2; mi++) {
                const int ro = (wm * 64 + mi * 32 + l31) * BK + ksw;
                ah[mi] = *(const bf16x8*)&sAh[ro];
                al[mi] = *(const bf16x8*)&sAl[ro];
            }
#pragma unroll
            for (int nj = 0; nj < 2; nj++) {
                const int ro = (wn * 64 + nj * 32 + l31) * BK + ksw;
                bh2[nj] = *(const bf16x8*)&sBh[ro];
                bl2[nj] = *(const bf16x8*)&sBl[ro];
            }
#pragma unroll
            for (int mi = 0; mi < 2; mi++)
#pragma unroll
                for (int nj = 0; nj < 2; nj++) {
                    acc[mi][nj] = __builtin_amdgcn_mfma_f32_32x32x16_bf16(al[mi], bh2[nj], acc[mi][nj], 0, 0, 0);
                    acc[mi][nj] = __builtin_amdgcn_mfma_f32_32x32x16_bf16(ah[mi], bl2[nj], acc[mi][nj], 0, 0, 0);
                    acc[mi][nj] = __builtin_amdgcn_mfma_f32_32x32x16_bf16(ah[mi], bh2[nj], acc[mi][nj], 0, 0, 0);
                }
        }
    }

#pragma unroll
    for (int mi = 0; mi < 2; mi++)
#pragma unroll
        for (int nj = 0; nj < 2; nj++) {
            const int cg = bn + wn * 64 + nj * 32 + l31;
            const float bv = HAS_BIAS ? bias[cg] : 0.0f;
#pragma unroll
            for (int r = 0; r < 16; r++) {
                const int rg = bm + wm * 64 + mi * 32 + (r & 3) + 8 * (r >> 2) + 4 * lhi;
                const float v = acc[mi][nj][r] + bv;
                const size_t idx = (size_t)rg * N + cg;
                if (HILO) {
                    const bf16 hh = (bf16)v;
                    Ch[idx] = hh;
                    Cl[idx] = (bf16)(v - (float)hh);
                } else {
                    Cf[idx] = v;
                }
            }
        }
}

// ---------------------------------------------------------------------------
// Score GEMM: split precision, 4x2 wave tile (wave = 128x64), block 128x256.
__global__ __launch_bounds__(256, 2) void gemm_score(
    const bf16* __restrict__ Ah, const bf16* __restrict__ Al,
    const bf16* __restrict__ Bh, const bf16* __restrict__ Bl,
    float* __restrict__ Cf, int N, int K)
{
    __shared__ bf16 sAh[128 * BK], sAl[128 * BK], sBh[256 * BK], sBl[256 * BK];
    const int t    = threadIdx.x;
    const int wave = t >> 6;
    const int lane = t & 63;
    const int l31  = lane & 31;
    const int lhi  = lane >> 5;
    const int bm   = blockIdx.y * 128;
    const int bn   = blockIdx.x * 256;
    const int srow = t >> 2;
    const int gseg = (t & 3) ^ ((srow >> 1) & 3);
    const int rsw  = (l31 >> 1) & 3;

    const size_t offA = (size_t)(bm + srow) * K + gseg * 8;
    const size_t offB = (size_t)(bn + srow) * K + gseg * 8;
    char* lAh = (char*)sAh + wave * 1024;
    char* lAl = (char*)sAl + wave * 1024;
    char* lBh = (char*)sBh + wave * 1024;
    char* lBl = (char*)sBl + wave * 1024;

    f32x16 acc[4][2] = {};

    for (int k0 = 0; k0 < K; k0 += BK) {
        __syncthreads();
        gld_lds16(Ah + offA + k0,                  lAh);
        gld_lds16(Ah + offA + (size_t)64 * K + k0, lAh + 4096);
        gld_lds16(Al + offA + k0,                  lAl);
        gld_lds16(Al + offA + (size_t)64 * K + k0, lAl + 4096);
#pragma unroll
        for (int rb = 0; rb < 4; rb++) {
            gld_lds16(Bh + offB + (size_t)(64 * rb) * K + k0, lBh + rb * 4096);
            gld_lds16(Bl + offB + (size_t)(64 * rb) * K + k0, lBl + rb * 4096);
        }
        __syncthreads();
#pragma unroll
        for (int kh = 0; kh < 2; kh++) {
            const int ksw = ((kh * 2 + lhi) ^ rsw) * 8;
            bf16x8 ah[4], al[4], bh2[2], bl2[2];
#pragma unroll
            for (int mi = 0; mi < 4; mi++) {
                const int ro = (mi * 32 + l31) * BK + ksw;
                ah[mi] = *(const bf16x8*)&sAh[ro];
                al[mi] = *(const bf16x8*)&sAl[ro];
            }
#pragma unroll
            for (int nj = 0; nj < 2; nj++) {
                const int ro = (wave * 64 + nj * 32 + l31) * BK + ksw;
                bh2[nj] = *(const bf16x8*)&sBh[ro];
                bl2[nj] = *(const bf16x8*)&sBl[ro];
            }
#pragma unroll
            for (int mi = 0; mi < 4; mi++)
#pragma unroll
                for (int nj = 0; nj < 2; nj++) {
                    acc[mi][nj] = __builtin_amdgcn_mfma_f32_32x32x16_bf16(al[mi], bh2[nj], acc[mi][nj], 0, 0, 0);
                    acc[mi][nj] = __builtin_amdgcn_mfma_f32_32x32x16_bf16(ah[mi], bl2[nj], acc[mi][nj], 0, 0, 0);
                    acc[mi][nj] = __builtin_amdgcn_mfma_f32_32x32x16_bf16(ah[mi], bh2[nj], acc[mi][nj], 0, 0, 0);
                }
        }
    }

#pragma unroll
    for (int mi = 0; mi < 4; mi++)
#pragma unroll
        for (int nj = 0; nj < 2; nj++) {
            const int cg = bn + wave * 64 + nj * 32 + l31;
#pragma unroll
            for (int r = 0; r < 16; r++) {
                const int rg = bm + mi * 32 + (r & 3) + 8 * (r >> 2) + 4 * lhi;
                Cf[(size_t)rg * N + cg] = acc[mi][nj][r];
            }
        }
}

// ---------------------------------------------------------------------------
__device__ __forceinline__ float wred_max(float v) {
#pragma unroll
    for (int off = 32; off > 0; off >>= 1) v = fmaxf(v, __shfl_xor(v, off));
    return v;
}
__device__ __forceinline__ float wred_sum(float v) {
#pragma unroll
    for (int off = 32; off > 0; off >>= 1) v += __shfl_xor(v, off);
    return v;
}

// Fused double softmax, vectorized (16 contiguous cols/thread).
// p2 fp32 stored nontemporal (never re-read; ctx consumes scoreb bf16).
__global__ __launch_bounds__(256) void softmax2_kernel(
    float* __restrict__ score, const int* __restrict__ mask,
    const float* __restrict__ wei, bf16* __restrict__ scoreb)
{
    __shared__ float sred[4];
    const int row = blockIdx.x;
    const int t   = threadIdx.x;
    const size_t base = (size_t)row * NKK + (size_t)t * 16;
    const int wv = t >> 6, ln = t & 63;

    float l[16], w[16];
    unsigned mb = 0;
#pragma unroll
    for (int c = 0; c < 4; c++) {
        *(f32x4*)(l + 4 * c) = *(const f32x4*)(score + base + 4 * c);
        *(f32x4*)(w + 4 * c) = *(const f32x4*)(wei + base + 4 * c);
        i32x4 mv = *(const i32x4*)(mask + base + 4 * c);
#pragma unroll
        for (int j = 0; j < 4; j++) if (mv[j] != 0) mb |= 1u << (4 * c + j);
    }

    // pass 1
    float mx = -__builtin_inff();
#pragma unroll
    for (int s = 0; s < 16; s++) if (mb & (1u << s)) mx = fmaxf(mx, l[s]);
    mx = wred_max(mx);
    if (ln == 0) sred[wv] = mx;
    __syncthreads();
    mx = fmaxf(fmaxf(sred[0], sred[1]), fmaxf(sred[2], sred[3]));
    __syncthreads();
    float sum = 0.f;
#pragma unroll
    for (int s = 0; s < 16; s++) {
        const float e = (mb & (1u << s)) ? __expf(l[s] - mx) : 0.f;
        l[s] = e; sum += e;
    }
    sum = wred_sum(sum);
    if (ln == 0) sred[wv] = sum;
    __syncthreads();
    sum = sred[0] + sred[1] + sred[2] + sred[3];
    __syncthreads();
    const float inv1 = 1.0f / sum;

#pragma unroll
    for (int s = 0; s < 16; s++) l[s] = l[s] * inv1 * w[s];

    // pass 2
    float mx2 = -__builtin_inff();
#pragma unroll
    for (int s = 0; s < 16; s++) if (mb & (1u << s)) mx2 = fmaxf(mx2, l[s]);
    mx2 = wred_max(mx2);
    if (ln == 0) sred[wv] = mx2;
    __syncthreads();
    mx2 = fmaxf(fmaxf(sred[0], sred[1]), fmaxf(sred[2], sred[3]));
    __syncthreads();
    float sum2 = 0.f;
#pragma unroll
    for (int s = 0; s < 16; s++) {
        const float e = (mb & (1u << s)) ? __expf(l[s] - mx2) : 0.f;
        l[s] = e; sum2 += e;
    }
    sum2 = wred_sum(sum2);
    if (ln == 0) sred[wv] = sum2;
    __syncthreads();
    sum2 = sred[0] + sred[1] + sred[2] + sred[3];
    const float inv2 = 1.0f / sum2;

#pragma unroll
    for (int c = 0; c < 4; c++) {
        f32x4 pv;
#pragma unroll
        for (int j = 0; j < 4; j++) pv[j] = l[4 * c + j] * inv2;
        __builtin_nontemporal_store(pv, (f32x4*)(score + base + 4 * c));
#pragma unroll
        for (int j = 0; j < 4; j++) l[4 * c + j] = pv[j];
    }
    bf16x8 b0, b1;
#pragma unroll
    for (int j = 0; j < 8; j++) { b0[j] = (bf16)l[j]; b1[j] = (bf16)l[8 + j]; }
    *(bf16x8*)(scoreb + base)     = b0;
    *(bf16x8*)(scoreb + base + 8) = b1;
}

// ---------------------------------------------------------------------------
extern "C" void kernel_launch(void* const* d_in, const int* in_sizes, int n_in,
                              void* d_out, int out_size, void* d_ws, size_t ws_size,
                              hipStream_t stream)
{
    (void)in_sizes; (void)n_in; (void)out_size;
    const float* q    = (const float*)d_in[0];
    const float* k    = (const float*)d_in[1];
    const int*   mask = (const int*)  d_in[2];
    const float* wei  = (const float*)d_in[3];
    const float* Wq   = (const float*)d_in[4];
    const float* bq   = (const float*)d_in[5];
    const float* Wk   = (const float*)d_in[6];
    const float* bk   = (const float*)d_in[7];
    const float* Wp   = (const float*)d_in[8];
    const float* bp   = (const float*)d_in[9];

    float* out   = (float*)d_out;
    float* score = (float*)d_out + (size_t)NQ * EMB;

    char* ws = (char*)d_ws;
    size_t off = 0;
    auto alloc = [&](size_t bytes) -> char* {
        char* p = ws + off; off += (bytes + 255) & ~(size_t)255; return p;
    };
    const size_t n_qk = (size_t)NQ * EMB;
    const size_t n_w  = (size_t)EMB * EMB;
    const size_t n_sc = (size_t)NQ * NKK;

    bf16* qh   = (bf16*)alloc(n_qk * 2);
    bf16* ql   = (bf16*)alloc(n_qk * 2);
    bf16* kh   = (bf16*)alloc(n_qk * 2);
    bf16* kl   = (bf16*)alloc(n_qk * 2);
    bf16* qxh  = (bf16*)alloc(n_qk * 2);
    bf16* qxl  = (bf16*)alloc(n_qk * 2);
    bf16* kxh  = (bf16*)alloc(n_qk * 2);
    bf16* kxl  = (bf16*)alloc(n_qk * 2);
    bf16* Wqh  = (bf16*)alloc(n_w * 2);
    bf16* Wql  = (bf16*)alloc(n_w * 2);
    bf16* Wkh  = (bf16*)alloc(n_w * 2);
    bf16* Wkl  = (bf16*)alloc(n_w * 2);
    bf16* Wpb  = (bf16*)alloc(n_w * 2);
    bf16* Wpl  = (bf16*)alloc(n_w * 2);
    bf16* kxTb = (bf16*)alloc(n_qk * 2);
    bf16* ctxb = (bf16*)alloc(n_qk * 2);
    bf16* scoreb = (bf16*)alloc(n_sc * 2);
    const size_t base_off = off;
    float* P = (float*)alloc(2 * n_qk * 4);   // 33.5 MB partials (split-K=2)
    const bool ws_ok = (off <= ws_size);
    if (base_off > ws_size) return;

    const int MN = (int)n_qk;

    // 1) prep: all 5 hi/lo splits in one launch
    prep_all<<<dim3(n_qk / 1024, 5), 256, 0, stream>>>(
        q, k, Wq, Wk, Wp,
        qh, ql, kh, kl, Wqh, Wql, Wkh, Wkl, Wpb, Wpl,
        (int)n_qk, (int)n_w);

    // 2) projections: batched z=2, direct bias + hi/lo epilogue (R5 optimum)
    gemm_bt_split<1, 1, 1><<<dim3(EMB / BN, NQ / BM, 2), 256, 0, stream>>>(
        qh, ql, Wqh, Wql, bq, qxh, qxl,
        kh, kl, Wkh, Wkl, bk, kxh, kxl,
        nullptr, NQ, EMB, EMB);

    // 3) kx^T for ctx GEMM B-operand
    transpose_bf16<<<dim3(EMB / 32, NKK / 32), 256, 0, stream>>>(kxh, kxTb, NKK, EMB);

    // 4) score logits = qx kx^T (4x2-tile split kernel, fp32 into d_out)
    gemm_score<<<dim3(NKK / 256, NQ / 128), 256, 0, stream>>>(
        qxh, qxl, kxh, kxl, score, NKK, EMB);

    // 5) fused double softmax (vectorized, mask int4, p2 nontemporal)
    softmax2_kernel<<<dim3(NQ), 256, 0, stream>>>(score, mask, wei, scoreb);

    // 6) ctx = p2 @ kx  (split-K=2; R5 optimum)
    if (ws_ok) {
        gemm_bt<2, 0, 0><<<dim3(EMB / BN, NQ / BM, 2), 256, 0, stream>>>(
            scoreb, kxTb, nullptr, P, nullptr, NQ, EMB, NKK / 2, NKK, NKK);
        reduce_k<2, 0><<<dim3(MN / 1024), 256, 0, stream>>>(
            P, nullptr, nullptr, ctxb, MN, EMB);
    } else {
        gemm_bt<0, 0, 1><<<dim3(EMB / BN, NQ / BM), 256, 0, stream>>>(
            scoreb, kxTb, nullptr, nullptr, ctxb, NQ, EMB, NKK, NKK, NKK);
    }

    // 7) out = ctx @ Wp^T + bp  (split-K=2; R5 optimum)
    if (ws_ok) {
        gemm_bt<2, 0, 0><<<dim3(EMB / BN, NQ / BM, 2), 256, 0, stream>>>(
            ctxb, Wpb, nullptr, P, nullptr, NQ, EMB, EMB / 2, EMB, EMB);
        reduce_k<2, 1><<<dim3(MN / 1024), 256, 0, stream>>>(
            P, bp, out, nullptr, MN, EMB);
    } else {
        gemm_bt<0, 1, 0><<<dim3(EMB / BN, NQ / BM), 256, 0, stream>>>(
            ctxb, Wpb, bp, out, nullptr, NQ, EMB, EMB, EMB, EMB);
    }
}

// Round 9
// 507.891 us; speedup vs baseline: 1.1139x; 1.0091x over previous
//
#include <hip/hip_runtime.h>

// ---------------------------------------------------------------------------
// Attention_73813307949177
//   kx = k Wk^T + bk ; qx = q Wq^T + bq
//   score = softmax2(softmax1(qx kx^T + bias)*wei + bias)
//   out = (score kx) Wp^T + bp  ==  score (kx Wp^T) + bp   [associativity]
// Outputs (concat): out [4096,1024] fp32, score [4096,4096] fp32
//
// R8 -> R9: algebraic restructure of the tail:
//   kxpT = Wp kx^T  (gemm_bt A=Wp B=kx -> [1024x4096] bf16, B^T layout direct,
//                    kills the transpose kernel)
//   out  = p2 kxp + bp  (one split-K2 GEMM + reduce)
// Deletes ctx GEMM + ctx reduce + out GEMM + out reduce + transpose
// (11 -> 7 dispatches, -34.4 GF, -2 intermediate round-trips).
// ---------------------------------------------------------------------------

typedef __bf16 bf16;
typedef __bf16 bf16x8 __attribute__((ext_vector_type(8)));
typedef __bf16 bf16x4 __attribute__((ext_vector_type(4)));
typedef float  f32x4  __attribute__((ext_vector_type(4)));
typedef float  f32x16 __attribute__((ext_vector_type(16)));
typedef int    i32x4  __attribute__((ext_vector_type(4)));

typedef __attribute__((address_space(1))) void as1_void;
typedef __attribute__((address_space(3))) void as3_void;

#define NQ  4096
#define NKK 4096
#define EMB 1024

#define BM 128
#define BN 128
#define BK 32

__device__ __forceinline__ void gld_lds16(const void* g, void* l) {
    __builtin_amdgcn_global_load_lds((as1_void*)g, (as3_void*)l, 16, 0, 0);
}

// ---------------------------------------------------------------------------
// prep: fp32 -> bf16 hi/lo split; 5 tensors batched via blockIdx.y
__global__ __launch_bounds__(256) void prep_all(
    const float* __restrict__ q, const float* __restrict__ k,
    const float* __restrict__ Wq, const float* __restrict__ Wk, const float* __restrict__ Wp,
    bf16* __restrict__ qh, bf16* __restrict__ ql,
    bf16* __restrict__ kh, bf16* __restrict__ kl,
    bf16* __restrict__ Wqh, bf16* __restrict__ Wql,
    bf16* __restrict__ Wkh, bf16* __restrict__ Wkl,
    bf16* __restrict__ Wph, bf16* __restrict__ Wpl,
    int nqk, int nw)
{
    const int z = blockIdx.y;
    const float* s; bf16* h; bf16* l; int n;
    switch (z) {
        case 0:  s = q;  h = qh;  l = ql;  n = nqk; break;
        case 1:  s = k;  h = kh;  l = kl;  n = nqk; break;
        case 2:  s = Wq; h = Wqh; l = Wql; n = nw;  break;
        case 3:  s = Wk; h = Wkh; l = Wkl; n = nw;  break;
        default: s = Wp; h = Wph; l = Wpl; n = nw;  break;
    }
    const int i = (blockIdx.x * 256 + threadIdx.x) * 4;
    if (i >= n) return;
    f32x4 v = *(const f32x4*)(s + i);
    bf16x4 hv, lv;
#pragma unroll
    for (int c = 0; c < 4; c++) {
        float x = v[c];
        bf16 hh = (bf16)x;
        hv[c] = hh;
        lv[c] = (bf16)(x - (float)hh);
    }
    *(bf16x4*)(h + i) = hv;
    *(bf16x4*)(l + i) = lv;
}

// ---------------------------------------------------------------------------
// reduce over NS partial slices. MODE 0: sum->bf16. MODE 1: sum+bias->f32.
template<int NS, int MODE>
__global__ __launch_bounds__(256) void reduce_k(
    const float* __restrict__ P, const float* __restrict__ bias,
    float* __restrict__ of, bf16* __restrict__ oh, int n, int Nld)
{
    const int i = (blockIdx.x * 256 + threadIdx.x) * 4;
    if (i >= n) return;
    f32x4 v = *(const f32x4*)(P + i);
#pragma unroll
    for (int s = 1; s < NS; s++)
        v += *(const f32x4*)(P + (size_t)s * n + i);
    if (MODE == 1)
        v += *(const f32x4*)(bias + (i & (Nld - 1)));
    if (MODE == 0) {
        bf16x4 o;
#pragma unroll
        for (int c = 0; c < 4; c++) o[c] = (bf16)v[c];
        *(bf16x4*)(oh + i) = o;
    } else {
        *(f32x4*)(of + i) = v;
    }
}

// ---------------------------------------------------------------------------
// Plain bf16 gemm_bt (32x32x16 core, swizzled LDS): C = A[M,K] B[N,K]^T.
// NSPLIT>0: blockIdx.z = kz -> fp32 partial slice kz.
template<int NSPLIT, int HAS_BIAS, int OUT_BF16>
__global__ __launch_bounds__(256) void gemm_bt(
    const bf16* __restrict__ A, const bf16* __restrict__ B,
    const float* __restrict__ bias,
    float* __restrict__ Cf, bf16* __restrict__ Cb,
    int M, int N, int Ksub, int lda, int ldb)
{
    __shared__ bf16 sA[BM * BK];
    __shared__ bf16 sB[BN * BK];
    const int t    = threadIdx.x;
    const int wave = t >> 6;
    const int lane = t & 63;
    const int l31  = lane & 31;
    const int lhi  = lane >> 5;
    const int wm   = wave >> 1;
    const int wn   = wave & 1;
    const int bm   = blockIdx.y * BM;
    const int bn   = blockIdx.x * BN;
    const int srow = t >> 2;
    const int gseg = (t & 3) ^ ((srow >> 1) & 3);
    const int rsw  = (l31 >> 1) & 3;
    const int kz   = (NSPLIT > 0) ? (int)blockIdx.z : 0;

    A += (size_t)kz * Ksub;
    B += (size_t)kz * Ksub;
    if (NSPLIT > 0) Cf += (size_t)kz * M * N;

    const bf16* ga = A + (size_t)(bm + srow) * lda + gseg * 8;
    const bf16* gb = B + (size_t)(bn + srow) * ldb + gseg * 8;
    char* lA = (char*)sA + wave * 1024;
    char* lB = (char*)sB + wave * 1024;

    f32x16 acc[2][2] = {};

    for (int k0 = 0; k0 < Ksub; k0 += BK) {
        __syncthreads();
        gld_lds16(ga + k0,                      lA);
        gld_lds16(ga + (size_t)64 * lda + k0,   lA + 4096);
        gld_lds16(gb + k0,                      lB);
        gld_lds16(gb + (size_t)64 * ldb + k0,   lB + 4096);
        __syncthreads();
        bf16x8 af[2][2], bfr[2][2];
#pragma unroll
        for (int mi = 0; mi < 2; mi++)
#pragma unroll
            for (int kh = 0; kh < 2; kh++)
                af[mi][kh] = *(const bf16x8*)
                    &sA[(wm * 64 + mi * 32 + l31) * BK + ((kh * 2 + lhi) ^ rsw) * 8];
#pragma unroll
        for (int nj = 0; nj < 2; nj++)
#pragma unroll
            for (int kh = 0; kh < 2; kh++)
                bfr[nj][kh] = *(const bf16x8*)
                    &sB[(wn * 64 + nj * 32 + l31) * BK + ((kh * 2 + lhi) ^ rsw) * 8];
#pragma unroll
        for (int kh = 0; kh < 2; kh++)
#pragma unroll
            for (int mi = 0; mi < 2; mi++)
#pragma unroll
                for (int nj = 0; nj < 2; nj++)
                    acc[mi][nj] = __builtin_amdgcn_mfma_f32_32x32x16_bf16(
                        af[mi][kh], bfr[nj][kh], acc[mi][nj], 0, 0, 0);
    }

#pragma unroll
    for (int mi = 0; mi < 2; mi++)
#pragma unroll
        for (int nj = 0; nj < 2; nj++) {
            const int cg = bn + wn * 64 + nj * 32 + l31;
            const float bv = HAS_BIAS ? bias[cg] : 0.0f;
#pragma unroll
            for (int r = 0; r < 16; r++) {
                const int rg = bm + wm * 64 + mi * 32 + (r & 3) + 8 * (r >> 2) + 4 * lhi;
                const float v = acc[mi][nj][r] + bv;
                const size_t idx = (size_t)rg * N + cg;
                if (NSPLIT > 0)    Cf[idx] = v;
                else if (OUT_BF16) Cb[idx] = (bf16)v;
                else               Cf[idx] = v;
            }
        }
}

// ---------------------------------------------------------------------------
// Split-precision gemm_bt (32x32x16, 2x2 wave tile; AlBh + AhBl + AhBh).
// Projections: BATCH via blockIdx.z, direct bias + hi/lo epilogue.
template<int BATCH, int HAS_BIAS, int HILO>
__global__ __launch_bounds__(256) void gemm_bt_split(
    const bf16* __restrict__ Ah0, const bf16* __restrict__ Al0,
    const bf16* __restrict__ Bh0, const bf16* __restrict__ Bl0,
    const float* __restrict__ bias0, bf16* __restrict__ Ch0, bf16* __restrict__ Cl0,
    const bf16* __restrict__ Ah1, const bf16* __restrict__ Al1,
    const bf16* __restrict__ Bh1, const bf16* __restrict__ Bl1,
    const float* __restrict__ bias1, bf16* __restrict__ Ch1, bf16* __restrict__ Cl1,
    float* __restrict__ Cf,
    int M, int N, int K)
{
    __shared__ bf16 sAh[BM * BK], sAl[BM * BK], sBh[BN * BK], sBl[BN * BK];
    const int t    = threadIdx.x;
    const int wave = t >> 6;
    const int lane = t & 63;
    const int l31  = lane & 31;
    const int lhi  = lane >> 5;
    const int wm   = wave >> 1;
    const int wn   = wave & 1;
    const int bm   = blockIdx.y * BM;
    const int bn   = blockIdx.x * BN;
    const int srow = t >> 2;
    const int gseg = (t & 3) ^ ((srow >> 1) & 3);
    const int rsw  = (l31 >> 1) & 3;

    const int mt = BATCH ? (int)blockIdx.z : 0;

    const bf16* Ah = (BATCH && mt) ? Ah1 : Ah0;
    const bf16* Al = (BATCH && mt) ? Al1 : Al0;
    const bf16* Bh = (BATCH && mt) ? Bh1 : Bh0;
    const bf16* Bl = (BATCH && mt) ? Bl1 : Bl0;
    const float* bias = (BATCH && mt) ? bias1 : bias0;
    bf16* Ch = (BATCH && mt) ? Ch1 : Ch0;
    bf16* Cl = (BATCH && mt) ? Cl1 : Cl0;

    const size_t offA = (size_t)(bm + srow) * K + gseg * 8;
    const size_t offB = (size_t)(bn + srow) * K + gseg * 8;
    char* lAh = (char*)sAh + wave * 1024;
    char* lAl = (char*)sAl + wave * 1024;
    char* lBh = (char*)sBh + wave * 1024;
    char* lBl = (char*)sBl + wave * 1024;

    f32x16 acc[2][2] = {};

    for (int k0 = 0; k0 < K; k0 += BK) {
        __syncthreads();
        gld_lds16(Ah + offA + k0,                  lAh);
        gld_lds16(Ah + offA + (size_t)64 * K + k0, lAh + 4096);
        gld_lds16(Al + offA + k0,                  lAl);
        gld_lds16(Al + offA + (size_t)64 * K + k0, lAl + 4096);
        gld_lds16(Bh + offB + k0,                  lBh);
        gld_lds16(Bh + offB + (size_t)64 * K + k0, lBh + 4096);
        gld_lds16(Bl + offB + k0,                  lBl);
        gld_lds16(Bl + offB + (size_t)64 * K + k0, lBl + 4096);
        __syncthreads();
#pragma unroll
        for (int kh = 0; kh < 2; kh++) {
            const int ksw = ((kh * 2 + lhi) ^ rsw) * 8;
            bf16x8 ah[2], al[2], bh2[2], bl2[2];
#pragma unroll
            for (int mi = 0; mi < 2; mi++) {
                const int ro = (wm * 64 + mi * 32 + l31) * BK + ksw;
                ah[mi] = *(const bf16x8*)&sAh[ro];
                al[mi] = *(const bf16x8*)&sAl[ro];
            }
#pragma unroll
            for (int nj = 0; nj < 2; nj++) {
                const int ro = (wn * 64 + nj * 32 + l31) * BK + ksw;
                bh2[nj] = *(const bf16x8*)&sBh[ro];
                bl2[nj] = *(const bf16x8*)&sBl[ro];
            }
#pragma unroll
            for (int mi = 0; mi < 2; mi++)
#pragma unroll
                for (int nj = 0; nj < 2; nj++) {
                    acc[mi][nj] = __builtin_amdgcn_mfma_f32_32x32x16_bf16(al[mi], bh2[nj], acc[mi][nj], 0, 0, 0);
                    acc[mi][nj] = __builtin_amdgcn_mfma_f32_32x32x16_bf16(ah[mi], bl2[nj], acc[mi][nj], 0, 0, 0);
                    acc[mi][nj] = __builtin_amdgcn_mfma_f32_32x32x16_bf16(ah[mi], bh2[nj], acc[mi][nj], 0, 0, 0);
                }
        }
    }

#pragma unroll
    for (int mi = 0; mi < 2; mi++)
#pragma unroll
        for (int nj = 0; nj < 2; nj++) {
            const int cg = bn + wn * 64 + nj * 32 + l31;
            const float bv = HAS_BIAS ? bias[cg] : 0.0f;
#pragma unroll
            for (int r = 0; r < 16; r++) {
                const int rg = bm + wm * 64 + mi * 32 + (r & 3) + 8 * (r >> 2) + 4 * lhi;
                const float v = acc[mi][nj][r] + bv;
                const size_t idx = (size_t)rg * N + cg;
                if (HILO) {
                    const bf16 hh = (bf16)v;
                    Ch[idx] = hh;
                    Cl[idx] = (bf16)(v - (float)hh);
                } else {
                    Cf[idx] = v;
                }
            }
        }
}

// ---------------------------------------------------------------------------
// Score GEMM: split precision, 4x2 wave tile (wave = 128x64), block 128x256.
__global__ __launch_bounds__(256, 2) void gemm_score(
    const bf16* __restrict__ Ah, const bf16* __restrict__ Al,
    const bf16* __restrict__ Bh, const bf16* __restrict__ Bl,
    float* __restrict__ Cf, int N, int K)
{
    __shared__ bf16 sAh[128 * BK], sAl[128 * BK], sBh[256 * BK], sBl[256 * BK];
    const int t    = threadIdx.x;
    const int wave = t >> 6;
    const int lane = t & 63;
    const int l31  = lane & 31;
    const int lhi  = lane >> 5;
    const int bm   = blockIdx.y * 128;
    const int bn   = blockIdx.x * 256;
    const int srow = t >> 2;
    const int gseg = (t & 3) ^ ((srow >> 1) & 3);
    const int rsw  = (l31 >> 1) & 3;

    const size_t offA = (size_t)(bm + srow) * K + gseg * 8;
    const size_t offB = (size_t)(bn + srow) * K + gseg * 8;
    char* lAh = (char*)sAh + wave * 1024;
    char* lAl = (char*)sAl + wave * 1024;
    char* lBh = (char*)sBh + wave * 1024;
    char* lBl = (char*)sBl + wave * 1024;

    f32x16 acc[4][2] = {};

    for (int k0 = 0; k0 < K; k0 += BK) {
        __syncthreads();
        gld_lds16(Ah + offA + k0,                  lAh);
        gld_lds16(Ah + offA + (size_t)64 * K + k0, lAh + 4096);
        gld_lds16(Al + offA + k0,                  lAl);
        gld_lds16(Al + offA + (size_t)64 * K + k0, lAl + 4096);
#pragma unroll
        for (int rb = 0; rb < 4; rb++) {
            gld_lds16(Bh + offB + (size_t)(64 * rb) * K + k0, lBh + rb * 4096);
            gld_lds16(Bl + offB + (size_t)(64 * rb) * K + k0, lBl + rb * 4096);
        }
        __syncthreads();
#pragma unroll
        for (int kh = 0; kh < 2; kh++) {
            const int ksw = ((kh * 2 + lhi) ^ rsw) * 8;
            bf16x8 ah[4], al[4], bh2[2], bl2[2];
#pragma unroll
            for (int mi = 0; mi < 4; mi++) {
                const int ro = (mi * 32 + l31) * BK + ksw;
                ah[mi] = *(const bf16x8*)&sAh[ro];
                al[mi] = *(const bf16x8*)&sAl[ro];
            }
#pragma unroll
            for (int nj = 0; nj < 2; nj++) {
                const int ro = (wave * 64 + nj * 32 + l31) * BK + ksw;
                bh2[nj] = *(const bf16x8*)&sBh[ro];
                bl2[nj] = *(const bf16x8*)&sBl[ro];
            }
#pragma unroll
            for (int mi = 0; mi < 4; mi++)
#pragma unroll
                for (int nj = 0; nj < 2; nj++) {
                    acc[mi][nj] = __builtin_amdgcn_mfma_f32_32x32x16_bf16(al[mi], bh2[nj], acc[mi][nj], 0, 0, 0);
                    acc[mi][nj] = __builtin_amdgcn_mfma_f32_32x32x16_bf16(ah[mi], bl2[nj], acc[mi][nj], 0, 0, 0);
                    acc[mi][nj] = __builtin_amdgcn_mfma_f32_32x32x16_bf16(ah[mi], bh2[nj], acc[mi][nj], 0, 0, 0);
                }
        }
    }

#pragma unroll
    for (int mi = 0; mi < 4; mi++)
#pragma unroll
        for (int nj = 0; nj < 2; nj++) {
            const int cg = bn + wave * 64 + nj * 32 + l31;
#pragma unroll
            for (int r = 0; r < 16; r++) {
                const int rg = bm + mi * 32 + (r & 3) + 8 * (r >> 2) + 4 * lhi;
                Cf[(size_t)rg * N + cg] = acc[mi][nj][r];
            }
        }
}

// ---------------------------------------------------------------------------
__device__ __forceinline__ float wred_max(float v) {
#pragma unroll
    for (int off = 32; off > 0; off >>= 1) v = fmaxf(v, __shfl_xor(v, off));
    return v;
}
__device__ __forceinline__ float wred_sum(float v) {
#pragma unroll
    for (int off = 32; off > 0; off >>= 1) v += __shfl_xor(v, off);
    return v;
}

// Fused double softmax, vectorized (16 contiguous cols/thread).
__global__ __launch_bounds__(256) void softmax2_kernel(
    float* __restrict__ score, const int* __restrict__ mask,
    const float* __restrict__ wei, bf16* __restrict__ scoreb)
{
    __shared__ float sred[4];
    const int row = blockIdx.x;
    const int t   = threadIdx.x;
    const size_t base = (size_t)row * NKK + (size_t)t * 16;
    const int wv = t >> 6, ln = t & 63;

    float l[16], w[16];
    unsigned mb = 0;
#pragma unroll
    for (int c = 0; c < 4; c++) {
        *(f32x4*)(l + 4 * c) = *(const f32x4*)(score + base + 4 * c);
        *(f32x4*)(w + 4 * c) = *(const f32x4*)(wei + base + 4 * c);
        i32x4 mv = *(const i32x4*)(mask + base + 4 * c);
#pragma unroll
        for (int j = 0; j < 4; j++) if (mv[j] != 0) mb |= 1u << (4 * c + j);
    }

    // pass 1
    float mx = -__builtin_inff();
#pragma unroll
    for (int s = 0; s < 16; s++) if (mb & (1u << s)) mx = fmaxf(mx, l[s]);
    mx = wred_max(mx);
    if (ln == 0) sred[wv] = mx;
    __syncthreads();
    mx = fmaxf(fmaxf(sred[0], sred[1]), fmaxf(sred[2], sred[3]));
    __syncthreads();
    float sum = 0.f;
#pragma unroll
    for (int s = 0; s < 16; s++) {
        const float e = (mb & (1u << s)) ? __expf(l[s] - mx) : 0.f;
        l[s] = e; sum += e;
    }
    sum = wred_sum(sum);
    if (ln == 0) sred[wv] = sum;
    __syncthreads();
    sum = sred[0] + sred[1] + sred[2] + sred[3];
    __syncthreads();
    const float inv1 = 1.0f / sum;

#pragma unroll
    for (int s = 0; s < 16; s++) l[s] = l[s] * inv1 * w[s];

    // pass 2
    float mx2 = -__builtin_inff();
#pragma unroll
    for (int s = 0; s < 16; s++) if (mb & (1u << s)) mx2 = fmaxf(mx2, l[s]);
    mx2 = wred_max(mx2);
    if (ln == 0) sred[wv] = mx2;
    __syncthreads();
    mx2 = fmaxf(fmaxf(sred[0], sred[1]), fmaxf(sred[2], sred[3]));
    __syncthreads();
    float sum2 = 0.f;
#pragma unroll
    for (int s = 0; s < 16; s++) {
        const float e = (mb & (1u << s)) ? __expf(l[s] - mx2) : 0.f;
        l[s] = e; sum2 += e;
    }
    sum2 = wred_sum(sum2);
    if (ln == 0) sred[wv] = sum2;
    __syncthreads();
    sum2 = sred[0] + sred[1] + sred[2] + sred[3];
    const float inv2 = 1.0f / sum2;

#pragma unroll
    for (int c = 0; c < 4; c++) {
        f32x4 pv;
#pragma unroll
        for (int j = 0; j < 4; j++) pv[j] = l[4 * c + j] * inv2;
        __builtin_nontemporal_store(pv, (f32x4*)(score + base + 4 * c));
#pragma unroll
        for (int j = 0; j < 4; j++) l[4 * c + j] = pv[j];
    }
    bf16x8 b0, b1;
#pragma unroll
    for (int j = 0; j < 8; j++) { b0[j] = (bf16)l[j]; b1[j] = (bf16)l[8 + j]; }
    *(bf16x8*)(scoreb + base)     = b0;
    *(bf16x8*)(scoreb + base + 8) = b1;
}

// ---------------------------------------------------------------------------
extern "C" void kernel_launch(void* const* d_in, const int* in_sizes, int n_in,
                              void* d_out, int out_size, void* d_ws, size_t ws_size,
                              hipStream_t stream)
{
    (void)in_sizes; (void)n_in; (void)out_size;
    const float* q    = (const float*)d_in[0];
    const float* k    = (const float*)d_in[1];
    const int*   mask = (const int*)  d_in[2];
    const float* wei  = (const float*)d_in[3];
    const float* Wq   = (const float*)d_in[4];
    const float* bq   = (const float*)d_in[5];
    const float* Wk   = (const float*)d_in[6];
    const float* bk   = (const float*)d_in[7];
    const float* Wp   = (const float*)d_in[8];
    const float* bp   = (const float*)d_in[9];

    float* out   = (float*)d_out;
    float* score = (float*)d_out + (size_t)NQ * EMB;

    char* ws = (char*)d_ws;
    size_t off = 0;
    auto alloc = [&](size_t bytes) -> char* {
        char* p = ws + off; off += (bytes + 255) & ~(size_t)255; return p;
    };
    const size_t n_qk = (size_t)NQ * EMB;
    const size_t n_w  = (size_t)EMB * EMB;
    const size_t n_sc = (size_t)NQ * NKK;

    bf16* qh   = (bf16*)alloc(n_qk * 2);
    bf16* ql   = (bf16*)alloc(n_qk * 2);
    bf16* kh   = (bf16*)alloc(n_qk * 2);
    bf16* kl   = (bf16*)alloc(n_qk * 2);
    bf16* qxh  = (bf16*)alloc(n_qk * 2);
    bf16* qxl  = (bf16*)alloc(n_qk * 2);
    bf16* kxh  = (bf16*)alloc(n_qk * 2);
    bf16* kxl  = (bf16*)alloc(n_qk * 2);
    bf16* Wqh  = (bf16*)alloc(n_w * 2);
    bf16* Wql  = (bf16*)alloc(n_w * 2);
    bf16* Wkh  = (bf16*)alloc(n_w * 2);
    bf16* Wkl  = (bf16*)alloc(n_w * 2);
    bf16* Wpb  = (bf16*)alloc(n_w * 2);
    bf16* Wpl  = (bf16*)alloc(n_w * 2);
    bf16* kxpTb = (bf16*)alloc(n_qk * 2);   // kxpT = Wp kx^T  [1024 x 4096]
    bf16* scoreb = (bf16*)alloc(n_sc * 2);
    const size_t base_off = off;
    float* P = (float*)alloc(2 * n_qk * 4); // 33.5 MB partials (split-K=2)
    const bool ws_ok = (off <= ws_size);
    if (base_off > ws_size) return;

    const int MN = (int)n_qk;

    // 1) prep: all 5 hi/lo splits in one launch
    prep_all<<<dim3(n_qk / 1024, 5), 256, 0, stream>>>(
        q, k, Wq, Wk, Wp,
        qh, ql, kh, kl, Wqh, Wql, Wkh, Wkl, Wpb, Wpl,
        (int)n_qk, (int)n_w);

    // 2) projections: batched z=2, direct bias + hi/lo epilogue
    gemm_bt_split<1, 1, 1><<<dim3(EMB / BN, NQ / BM, 2), 256, 0, stream>>>(
        qh, ql, Wqh, Wql, bq, qxh, qxl,
        kh, kl, Wkh, Wkl, bk, kxh, kxl,
        nullptr, NQ, EMB, EMB);

    // 3) kxpT = Wp kx^T  (bf16, directly in B^T layout for step 6)
    //    C[n][m] = sum_k Wp[n,k] kx[m,k]  -> M=1024, N=4096, K=1024
    gemm_bt<0, 0, 1><<<dim3(NKK / BN, EMB / BM), 256, 0, stream>>>(
        Wpb, kxh, nullptr, nullptr, kxpTb, EMB, NKK, EMB, EMB, EMB);

    // 4) score logits = qx kx^T (4x2-tile split kernel, fp32 into d_out)
    gemm_score<<<dim3(NKK / 256, NQ / 128), 256, 0, stream>>>(
        qxh, qxl, kxh, kxl, score, NKK, EMB);

    // 5) fused double softmax (vectorized, mask int4, p2 nontemporal)
    softmax2_kernel<<<dim3(NQ), 256, 0, stream>>>(score, mask, wei, scoreb);

    // 6) out = p2 kxp + bp  (split-K=2 over K=4096)
    if (ws_ok) {
        gemm_bt<2, 0, 0><<<dim3(EMB / BN, NQ / BM, 2), 256, 0, stream>>>(
            scoreb, kxpTb, nullptr, P, nullptr, NQ, EMB, NKK / 2, NKK, NKK);
        reduce_k<2, 1><<<dim3(MN / 1024), 256, 0, stream>>>(
            P, bp, out, nullptr, MN, EMB);
    } else {
        gemm_bt<0, 1, 0><<<dim3(EMB / BN, NQ / BM), 256, 0, stream>>>(
            scoreb, kxpTb, bp, out, nullptr, NQ, EMB, NKK, NKK, NKK);
    }
}

// Round 10
// 488.527 us; speedup vs baseline: 1.1581x; 1.0396x over previous
//
#include <hip/hip_runtime.h>

// ---------------------------------------------------------------------------
// Attention_73813307949177
//   kx = k Wk^T + bk ; qx = q Wq^T + bq
//   score = softmax2(softmax1(qx kx^T + bias)*wei + bias)
//   out = score (kx Wp^T) + bp   [associativity, validated R9]
// Outputs (concat): out [4096,1024] fp32, score [4096,4096] fp32
//
// R9 -> R10: CONCURRENCY. kxpT = Wp kx^T is independent of the score GEMM
// (both only need proj outputs) but ran serially (+35us at 1 block/CU).
// Fused into one 768-block launch: blocks 0-511 = score (128x256, 4x2 wave
// tile, 48KB LDS), blocks 512-767 = kxpT (128x128, 2x2 tile, 16KB subset).
// kxpT soaks idle MFMA slots / LDS capacity (160-96=64KB/CU) under score.
// ---------------------------------------------------------------------------

typedef __bf16 bf16;
typedef __bf16 bf16x8 __attribute__((ext_vector_type(8)));
typedef __bf16 bf16x4 __attribute__((ext_vector_type(4)));
typedef float  f32x4  __attribute__((ext_vector_type(4)));
typedef float  f32x16 __attribute__((ext_vector_type(16)));
typedef int    i32x4  __attribute__((ext_vector_type(4)));

typedef __attribute__((address_space(1))) void as1_void;
typedef __attribute__((address_space(3))) void as3_void;

#define NQ  4096
#define NKK 4096
#define EMB 1024

#define BM 128
#define BN 128
#define BK 32

__device__ __forceinline__ void gld_lds16(const void* g, void* l) {
    __builtin_amdgcn_global_load_lds((as1_void*)g, (as3_void*)l, 16, 0, 0);
}

// ---------------------------------------------------------------------------
// prep: fp32 -> bf16 hi/lo split; 5 tensors batched via blockIdx.y
__global__ __launch_bounds__(256) void prep_all(
    const float* __restrict__ q, const float* __restrict__ k,
    const float* __restrict__ Wq, const float* __restrict__ Wk, const float* __restrict__ Wp,
    bf16* __restrict__ qh, bf16* __restrict__ ql,
    bf16* __restrict__ kh, bf16* __restrict__ kl,
    bf16* __restrict__ Wqh, bf16* __restrict__ Wql,
    bf16* __restrict__ Wkh, bf16* __restrict__ Wkl,
    bf16* __restrict__ Wph, bf16* __restrict__ Wpl,
    int nqk, int nw)
{
    const int z = blockIdx.y;
    const float* s; bf16* h; bf16* l; int n;
    switch (z) {
        case 0:  s = q;  h = qh;  l = ql;  n = nqk; break;
        case 1:  s = k;  h = kh;  l = kl;  n = nqk; break;
        case 2:  s = Wq; h = Wqh; l = Wql; n = nw;  break;
        case 3:  s = Wk; h = Wkh; l = Wkl; n = nw;  break;
        default: s = Wp; h = Wph; l = Wpl; n = nw;  break;
    }
    const int i = (blockIdx.x * 256 + threadIdx.x) * 4;
    if (i >= n) return;
    f32x4 v = *(const f32x4*)(s + i);
    bf16x4 hv, lv;
#pragma unroll
    for (int c = 0; c < 4; c++) {
        float x = v[c];
        bf16 hh = (bf16)x;
        hv[c] = hh;
        lv[c] = (bf16)(x - (float)hh);
    }
    *(bf16x4*)(h + i) = hv;
    *(bf16x4*)(l + i) = lv;
}

// ---------------------------------------------------------------------------
// reduce over NS partial slices. MODE 0: sum->bf16. MODE 1: sum+bias->f32.
template<int NS, int MODE>
__global__ __launch_bounds__(256) void reduce_k(
    const float* __restrict__ P, const float* __restrict__ bias,
    float* __restrict__ of, bf16* __restrict__ oh, int n, int Nld)
{
    const int i = (blockIdx.x * 256 + threadIdx.x) * 4;
    if (i >= n) return;
    f32x4 v = *(const f32x4*)(P + i);
#pragma unroll
    for (int s = 1; s < NS; s++)
        v += *(const f32x4*)(P + (size_t)s * n + i);
    if (MODE == 1)
        v += *(const f32x4*)(bias + (i & (Nld - 1)));
    if (MODE == 0) {
        bf16x4 o;
#pragma unroll
        for (int c = 0; c < 4; c++) o[c] = (bf16)v[c];
        *(bf16x4*)(oh + i) = o;
    } else {
        *(f32x4*)(of + i) = v;
    }
}

// ---------------------------------------------------------------------------
// Plain bf16 gemm_bt (32x32x16 core, swizzled LDS): C = A[M,K] B[N,K]^T.
// NSPLIT>0: blockIdx.z = kz -> fp32 partial slice kz.
template<int NSPLIT, int HAS_BIAS, int OUT_BF16>
__global__ __launch_bounds__(256) void gemm_bt(
    const bf16* __restrict__ A, const bf16* __restrict__ B,
    const float* __restrict__ bias,
    float* __restrict__ Cf, bf16* __restrict__ Cb,
    int M, int N, int Ksub, int lda, int ldb)
{
    __shared__ bf16 sA[BM * BK];
    __shared__ bf16 sB[BN * BK];
    const int t    = threadIdx.x;
    const int wave = t >> 6;
    const int lane = t & 63;
    const int l31  = lane & 31;
    const int lhi  = lane >> 5;
    const int wm   = wave >> 1;
    const int wn   = wave & 1;
    const int bm   = blockIdx.y * BM;
    const int bn   = blockIdx.x * BN;
    const int srow = t >> 2;
    const int gseg = (t & 3) ^ ((srow >> 1) & 3);
    const int rsw  = (l31 >> 1) & 3;
    const int kz   = (NSPLIT > 0) ? (int)blockIdx.z : 0;

    A += (size_t)kz * Ksub;
    B += (size_t)kz * Ksub;
    if (NSPLIT > 0) Cf += (size_t)kz * M * N;

    const bf16* ga = A + (size_t)(bm + srow) * lda + gseg * 8;
    const bf16* gb = B + (size_t)(bn + srow) * ldb + gseg * 8;
    char* lA = (char*)sA + wave * 1024;
    char* lB = (char*)sB + wave * 1024;

    f32x16 acc[2][2] = {};

    for (int k0 = 0; k0 < Ksub; k0 += BK) {
        __syncthreads();
        gld_lds16(ga + k0,                      lA);
        gld_lds16(ga + (size_t)64 * lda + k0,   lA + 4096);
        gld_lds16(gb + k0,                      lB);
        gld_lds16(gb + (size_t)64 * ldb + k0,   lB + 4096);
        __syncthreads();
        bf16x8 af[2][2], bfr[2][2];
#pragma unroll
        for (int mi = 0; mi < 2; mi++)
#pragma unroll
            for (int kh = 0; kh < 2; kh++)
                af[mi][kh] = *(const bf16x8*)
                    &sA[(wm * 64 + mi * 32 + l31) * BK + ((kh * 2 + lhi) ^ rsw) * 8];
#pragma unroll
        for (int nj = 0; nj < 2; nj++)
#pragma unroll
            for (int kh = 0; kh < 2; kh++)
                bfr[nj][kh] = *(const bf16x8*)
                    &sB[(wn * 64 + nj * 32 + l31) * BK + ((kh * 2 + lhi) ^ rsw) * 8];
#pragma unroll
        for (int kh = 0; kh < 2; kh++)
#pragma unroll
            for (int mi = 0; mi < 2; mi++)
#pragma unroll
                for (int nj = 0; nj < 2; nj++)
                    acc[mi][nj] = __builtin_amdgcn_mfma_f32_32x32x16_bf16(
                        af[mi][kh], bfr[nj][kh], acc[mi][nj], 0, 0, 0);
    }

#pragma unroll
    for (int mi = 0; mi < 2; mi++)
#pragma unroll
        for (int nj = 0; nj < 2; nj++) {
            const int cg = bn + wn * 64 + nj * 32 + l31;
            const float bv = HAS_BIAS ? bias[cg] : 0.0f;
#pragma unroll
            for (int r = 0; r < 16; r++) {
                const int rg = bm + wm * 64 + mi * 32 + (r & 3) + 8 * (r >> 2) + 4 * lhi;
                const float v = acc[mi][nj][r] + bv;
                const size_t idx = (size_t)rg * N + cg;
                if (NSPLIT > 0)    Cf[idx] = v;
                else if (OUT_BF16) Cb[idx] = (bf16)v;
                else               Cf[idx] = v;
            }
        }
}

// ---------------------------------------------------------------------------
// Split-precision gemm_bt (32x32x16, 2x2 wave tile; AlBh + AhBl + AhBh).
// Projections: BATCH via blockIdx.z, direct bias + hi/lo epilogue.
template<int BATCH, int HAS_BIAS, int HILO>
__global__ __launch_bounds__(256) void gemm_bt_split(
    const bf16* __restrict__ Ah0, const bf16* __restrict__ Al0,
    const bf16* __restrict__ Bh0, const bf16* __restrict__ Bl0,
    const float* __restrict__ bias0, bf16* __restrict__ Ch0, bf16* __restrict__ Cl0,
    const bf16* __restrict__ Ah1, const bf16* __restrict__ Al1,
    const bf16* __restrict__ Bh1, const bf16* __restrict__ Bl1,
    const float* __restrict__ bias1, bf16* __restrict__ Ch1, bf16* __restrict__ Cl1,
    float* __restrict__ Cf,
    int M, int N, int K)
{
    __shared__ bf16 sAh[BM * BK], sAl[BM * BK], sBh[BN * BK], sBl[BN * BK];
    const int t    = threadIdx.x;
    const int wave = t >> 6;
    const int lane = t & 63;
    const int l31  = lane & 31;
    const int lhi  = lane >> 5;
    const int wm   = wave >> 1;
    const int wn   = wave & 1;
    const int bm   = blockIdx.y * BM;
    const int bn   = blockIdx.x * BN;
    const int srow = t >> 2;
    const int gseg = (t & 3) ^ ((srow >> 1) & 3);
    const int rsw  = (l31 >> 1) & 3;

    const int mt = BATCH ? (int)blockIdx.z : 0;

    const bf16* Ah = (BATCH && mt) ? Ah1 : Ah0;
    const bf16* Al = (BATCH && mt) ? Al1 : Al0;
    const bf16* Bh = (BATCH && mt) ? Bh1 : Bh0;
    const bf16* Bl = (BATCH && mt) ? Bl1 : Bl0;
    const float* bias = (BATCH && mt) ? bias1 : bias0;
    bf16* Ch = (BATCH && mt) ? Ch1 : Ch0;
    bf16* Cl = (BATCH && mt) ? Cl1 : Cl0;

    const size_t offA = (size_t)(bm + srow) * K + gseg * 8;
    const size_t offB = (size_t)(bn + srow) * K + gseg * 8;
    char* lAh = (char*)sAh + wave * 1024;
    char* lAl = (char*)sAl + wave * 1024;
    char* lBh = (char*)sBh + wave * 1024;
    char* lBl = (char*)sBl + wave * 1024;

    f32x16 acc[2][2] = {};

    for (int k0 = 0; k0 < K; k0 += BK) {
        __syncthreads();
        gld_lds16(Ah + offA + k0,                  lAh);
        gld_lds16(Ah + offA + (size_t)64 * K + k0, lAh + 4096);
        gld_lds16(Al + offA + k0,                  lAl);
        gld_lds16(Al + offA + (size_t)64 * K + k0, lAl + 4096);
        gld_lds16(Bh + offB + k0,                  lBh);
        gld_lds16(Bh + offB + (size_t)64 * K + k0, lBh + 4096);
        gld_lds16(Bl + offB + k0,                  lBl);
        gld_lds16(Bl + offB + (size_t)64 * K + k0, lBl + 4096);
        __syncthreads();
#pragma unroll
        for (int kh = 0; kh < 2; kh++) {
            const int ksw = ((kh * 2 + lhi) ^ rsw) * 8;
            bf16x8 ah[2], al[2], bh2[2], bl2[2];
#pragma unroll
            for (int mi = 0; mi < 2; mi++) {
                const int ro = (wm * 64 + mi * 32 + l31) * BK + ksw;
                ah[mi] = *(const bf16x8*)&sAh[ro];
                al[mi] = *(const bf16x8*)&sAl[ro];
            }
#pragma unroll
            for (int nj = 0; nj < 2; nj++) {
                const int ro = (wn * 64 + nj * 32 + l31) * BK + ksw;
                bh2[nj] = *(const bf16x8*)&sBh[ro];
                bl2[nj] = *(const bf16x8*)&sBl[ro];
            }
#pragma unroll
            for (int mi = 0; mi < 2; mi++)
#pragma unroll
                for (int nj = 0; nj < 2; nj++) {
                    acc[mi][nj] = __builtin_amdgcn_mfma_f32_32x32x16_bf16(al[mi], bh2[nj], acc[mi][nj], 0, 0, 0);
                    acc[mi][nj] = __builtin_amdgcn_mfma_f32_32x32x16_bf16(ah[mi], bl2[nj], acc[mi][nj], 0, 0, 0);
                    acc[mi][nj] = __builtin_amdgcn_mfma_f32_32x32x16_bf16(ah[mi], bh2[nj], acc[mi][nj], 0, 0, 0);
                }
        }
    }

#pragma unroll
    for (int mi = 0; mi < 2; mi++)
#pragma unroll
        for (int nj = 0; nj < 2; nj++) {
            const int cg = bn + wn * 64 + nj * 32 + l31;
            const float bv = HAS_BIAS ? bias[cg] : 0.0f;
#pragma unroll
            for (int r = 0; r < 16; r++) {
                const int rg = bm + wm * 64 + mi * 32 + (r & 3) + 8 * (r >> 2) + 4 * lhi;
                const float v = acc[mi][nj][r] + bv;
                const size_t idx = (size_t)rg * N + cg;
                if (HILO) {
                    const bf16 hh = (bf16)v;
                    Ch[idx] = hh;
                    Cl[idx] = (bf16)(v - (float)hh);
                } else {
                    Cf[idx] = v;
                }
            }
        }
}

// ---------------------------------------------------------------------------
// FUSED: score GEMM (blocks 0..511) + kxpT GEMM (blocks 512..767).
// Score: split precision, 4x2 wave tile, block 128x256, 48KB LDS.
// kxpT:  plain bf16 C[m,n] = sum_k Wp[m,k] kx[n,k], 128x128, 16KB subset.
__global__ __launch_bounds__(256, 2) void gemm_score_kxp(
    const bf16* __restrict__ Ah, const bf16* __restrict__ Al,
    const bf16* __restrict__ Bh, const bf16* __restrict__ Bl,
    float* __restrict__ Cf,
    const bf16* __restrict__ Wp, const bf16* __restrict__ Kx,
    bf16* __restrict__ kxpT)
{
    __shared__ bf16 smem[24576];   // 48 KB
    const int t    = threadIdx.x;
    const int wave = t >> 6;
    const int lane = t & 63;
    const int l31  = lane & 31;
    const int lhi  = lane >> 5;
    const int srow = t >> 2;
    const int gseg = (t & 3) ^ ((srow >> 1) & 3);
    const int rsw  = (l31 >> 1) & 3;
    const int bid  = blockIdx.x;

    if (bid < 512) {
        // ---------------- score: logits = qx kx^T, N=NKK, K=EMB -------------
        bf16* sAh = smem;
        bf16* sAl = smem + 4096;
        bf16* sBh = smem + 8192;
        bf16* sBl = smem + 16384;
        const int bm = (bid >> 4) * 128;
        const int bn = (bid & 15) * 256;
        const int K  = EMB, N = NKK;

        const size_t offA = (size_t)(bm + srow) * K + gseg * 8;
        const size_t offB = (size_t)(bn + srow) * K + gseg * 8;
        char* lAh = (char*)sAh + wave * 1024;
        char* lAl = (char*)sAl + wave * 1024;
        char* lBh = (char*)sBh + wave * 1024;
        char* lBl = (char*)sBl + wave * 1024;

        f32x16 acc[4][2] = {};

        for (int k0 = 0; k0 < K; k0 += BK) {
            __syncthreads();
            gld_lds16(Ah + offA + k0,                  lAh);
            gld_lds16(Ah + offA + (size_t)64 * K + k0, lAh + 4096);
            gld_lds16(Al + offA + k0,                  lAl);
            gld_lds16(Al + offA + (size_t)64 * K + k0, lAl + 4096);
#pragma unroll
            for (int rb = 0; rb < 4; rb++) {
                gld_lds16(Bh + offB + (size_t)(64 * rb) * K + k0, lBh + rb * 4096);
                gld_lds16(Bl + offB + (size_t)(64 * rb) * K + k0, lBl + rb * 4096);
            }
            __syncthreads();
#pragma unroll
            for (int kh = 0; kh < 2; kh++) {
                const int ksw = ((kh * 2 + lhi) ^ rsw) * 8;
                bf16x8 a_h[4], a_l[4], b_h[2], b_l[2];
#pragma unroll
                for (int mi = 0; mi < 4; mi++) {
                    const int ro = (mi * 32 + l31) * BK + ksw;
                    a_h[mi] = *(const bf16x8*)&sAh[ro];
                    a_l[mi] = *(const bf16x8*)&sAl[ro];
                }
#pragma unroll
                for (int nj = 0; nj < 2; nj++) {
                    const int ro = (wave * 64 + nj * 32 + l31) * BK + ksw;
                    b_h[nj] = *(const bf16x8*)&sBh[ro];
                    b_l[nj] = *(const bf16x8*)&sBl[ro];
                }
#pragma unroll
                for (int mi = 0; mi < 4; mi++)
#pragma unroll
                    for (int nj = 0; nj < 2; nj++) {
                        acc[mi][nj] = __builtin_amdgcn_mfma_f32_32x32x16_bf16(a_l[mi], b_h[nj], acc[mi][nj], 0, 0, 0);
                        acc[mi][nj] = __builtin_amdgcn_mfma_f32_32x32x16_bf16(a_h[mi], b_l[nj], acc[mi][nj], 0, 0, 0);
                        acc[mi][nj] = __builtin_amdgcn_mfma_f32_32x32x16_bf16(a_h[mi], b_h[nj], acc[mi][nj], 0, 0, 0);
                    }
            }
        }

#pragma unroll
        for (int mi = 0; mi < 4; mi++)
#pragma unroll
            for (int nj = 0; nj < 2; nj++) {
                const int cg = bn + wave * 64 + nj * 32 + l31;
#pragma unroll
                for (int r = 0; r < 16; r++) {
                    const int rg = bm + mi * 32 + (r & 3) + 8 * (r >> 2) + 4 * lhi;
                    Cf[(size_t)rg * N + cg] = acc[mi][nj][r];
                }
            }
    } else {
        // ---------------- kxpT: C[m,n] = sum_k Wp[m,k] Kx[n,k] --------------
        // M=EMB(1024), N=NKK(4096), K=EMB(1024); bf16 out at kxpT[m*N+n].
        bf16* sA = smem;
        bf16* sB = smem + 4096;
        const int id = bid - 512;          // 0..255
        const int bn = (id & 31) * 128;    // over NKK/128 = 32
        const int bm = (id >> 5) * 128;    // over EMB/128 = 8
        const int K  = EMB, N = NKK;
        const int wm = wave >> 1;
        const int wn = wave & 1;

        const bf16* ga = Wp + (size_t)(bm + srow) * K + gseg * 8;
        const bf16* gb = Kx + (size_t)(bn + srow) * K + gseg * 8;
        char* lA = (char*)sA + wave * 1024;
        char* lB = (char*)sB + wave * 1024;

        f32x16 acc[2][2] = {};

        for (int k0 = 0; k0 < K; k0 += BK) {
            __syncthreads();
            gld_lds16(ga + k0,                    lA);
            gld_lds16(ga + (size_t)64 * K + k0,   lA + 4096);
            gld_lds16(gb + k0,                    lB);
            gld_lds16(gb + (size_t)64 * K + k0,   lB + 4096);
            __syncthreads();
            bf16x8 af[2][2], bfr[2][2];
#pragma unroll
            for (int mi = 0; mi < 2; mi++)
#pragma unroll
                for (int kh = 0; kh < 2; kh++)
                    af[mi][kh] = *(const bf16x8*)
                        &sA[(wm * 64 + mi * 32 + l31) * BK + ((kh * 2 + lhi) ^ rsw) * 8];
#pragma unroll
            for (int nj = 0; nj < 2; nj++)
#pragma unroll
                for (int kh = 0; kh < 2; kh++)
                    bfr[nj][kh] = *(const bf16x8*)
                        &sB[(wn * 64 + nj * 32 + l31) * BK + ((kh * 2 + lhi) ^ rsw) * 8];
#pragma unroll
            for (int kh = 0; kh < 2; kh++)
#pragma unroll
                for (int mi = 0; mi < 2; mi++)
#pragma unroll
                    for (int nj = 0; nj < 2; nj++)
                        acc[mi][nj] = __builtin_amdgcn_mfma_f32_32x32x16_bf16(
                            af[mi][kh], bfr[nj][kh], acc[mi][nj], 0, 0, 0);
        }

#pragma unroll
        for (int mi = 0; mi < 2; mi++)
#pragma unroll
            for (int nj = 0; nj < 2; nj++) {
                const int cg = bn + wn * 64 + nj * 32 + l31;
#pragma unroll
                for (int r = 0; r < 16; r++) {
                    const int rg = bm + wm * 64 + mi * 32 + (r & 3) + 8 * (r >> 2) + 4 * lhi;
                    kxpT[(size_t)rg * N + cg] = (bf16)acc[mi][nj][r];
                }
            }
    }
}

// ---------------------------------------------------------------------------
__device__ __forceinline__ float wred_max(float v) {
#pragma unroll
    for (int off = 32; off > 0; off >>= 1) v = fmaxf(v, __shfl_xor(v, off));
    return v;
}
__device__ __forceinline__ float wred_sum(float v) {
#pragma unroll
    for (int off = 32; off > 0; off >>= 1) v += __shfl_xor(v, off);
    return v;
}

// Fused double softmax, vectorized (16 contiguous cols/thread).
__global__ __launch_bounds__(256) void softmax2_kernel(
    float* __restrict__ score, const int* __restrict__ mask,
    const float* __restrict__ wei, bf16* __restrict__ scoreb)
{
    __shared__ float sred[4];
    const int row = blockIdx.x;
    const int t   = threadIdx.x;
    const size_t base = (size_t)row * NKK + (size_t)t * 16;
    const int wv = t >> 6, ln = t & 63;

    float l[16], w[16];
    unsigned mb = 0;
#pragma unroll
    for (int c = 0; c < 4; c++) {
        *(f32x4*)(l + 4 * c) = *(const f32x4*)(score + base + 4 * c);
        *(f32x4*)(w + 4 * c) = *(const f32x4*)(wei + base + 4 * c);
        i32x4 mv = *(const i32x4*)(mask + base + 4 * c);
#pragma unroll
        for (int j = 0; j < 4; j++) if (mv[j] != 0) mb |= 1u << (4 * c + j);
    }

    // pass 1
    float mx = -__builtin_inff();
#pragma unroll
    for (int s = 0; s < 16; s++) if (mb & (1u << s)) mx = fmaxf(mx, l[s]);
    mx = wred_max(mx);
    if (ln == 0) sred[wv] = mx;
    __syncthreads();
    mx = fmaxf(fmaxf(sred[0], sred[1]), fmaxf(sred[2], sred[3]));
    __syncthreads();
    float sum = 0.f;
#pragma unroll
    for (int s = 0; s < 16; s++) {
        const float e = (mb & (1u << s)) ? __expf(l[s] - mx) : 0.f;
        l[s] = e; sum += e;
    }
    sum = wred_sum(sum);
    if (ln == 0) sred[wv] = sum;
    __syncthreads();
    sum = sred[0] + sred[1] + sred[2] + sred[3];
    __syncthreads();
    const float inv1 = 1.0f / sum;

#pragma unroll
    for (int s = 0; s < 16; s++) l[s] = l[s] * inv1 * w[s];

    // pass 2
    float mx2 = -__builtin_inff();
#pragma unroll
    for (int s = 0; s < 16; s++) if (mb & (1u << s)) mx2 = fmaxf(mx2, l[s]);
    mx2 = wred_max(mx2);
    if (ln == 0) sred[wv] = mx2;
    __syncthreads();
    mx2 = fmaxf(fmaxf(sred[0], sred[1]), fmaxf(sred[2], sred[3]));
    __syncthreads();
    float sum2 = 0.f;
#pragma unroll
    for (int s = 0; s < 16; s++) {
        const float e = (mb & (1u << s)) ? __expf(l[s] - mx2) : 0.f;
        l[s] = e; sum2 += e;
    }
    sum2 = wred_sum(sum2);
    if (ln == 0) sred[wv] = sum2;
    __syncthreads();
    sum2 = sred[0] + sred[1] + sred[2] + sred[3];
    const float inv2 = 1.0f / sum2;

#pragma unroll
    for (int c = 0; c < 4; c++) {
        f32x4 pv;
#pragma unroll
        for (int j = 0; j < 4; j++) pv[j] = l[4 * c + j] * inv2;
        __builtin_nontemporal_store(pv, (f32x4*)(score + base + 4 * c));
#pragma unroll
        for (int j = 0; j < 4; j++) l[4 * c + j] = pv[j];
    }
    bf16x8 b0, b1;
#pragma unroll
    for (int j = 0; j < 8; j++) { b0[j] = (bf16)l[j]; b1[j] = (bf16)l[8 + j]; }
    *(bf16x8*)(scoreb + base)     = b0;
    *(bf16x8*)(scoreb + base + 8) = b1;
}

// ---------------------------------------------------------------------------
extern "C" void kernel_launch(void* const* d_in, const int* in_sizes, int n_in,
                              void* d_out, int out_size, void* d_ws, size_t ws_size,
                              hipStream_t stream)
{
    (void)in_sizes; (void)n_in; (void)out_size;
    const float* q    = (const float*)d_in[0];
    const float* k    = (const float*)d_in[1];
    const int*   mask = (const int*)  d_in[2];
    const float* wei  = (const float*)d_in[3];
    const float* Wq   = (const float*)d_in[4];
    const float* bq   = (const float*)d_in[5];
    const float* Wk   = (const float*)d_in[6];
    const float* bk   = (const float*)d_in[7];
    const float* Wp   = (const float*)d_in[8];
    const float* bp   = (const float*)d_in[9];

    float* out   = (float*)d_out;
    float* score = (float*)d_out + (size_t)NQ * EMB;

    char* ws = (char*)d_ws;
    size_t off = 0;
    auto alloc = [&](size_t bytes) -> char* {
        char* p = ws + off; off += (bytes + 255) & ~(size_t)255; return p;
    };
    const size_t n_qk = (size_t)NQ * EMB;
    const size_t n_w  = (size_t)EMB * EMB;
    const size_t n_sc = (size_t)NQ * NKK;

    bf16* qh   = (bf16*)alloc(n_qk * 2);
    bf16* ql   = (bf16*)alloc(n_qk * 2);
    bf16* kh   = (bf16*)alloc(n_qk * 2);
    bf16* kl   = (bf16*)alloc(n_qk * 2);
    bf16* qxh  = (bf16*)alloc(n_qk * 2);
    bf16* qxl  = (bf16*)alloc(n_qk * 2);
    bf16* kxh  = (bf16*)alloc(n_qk * 2);
    bf16* kxl  = (bf16*)alloc(n_qk * 2);
    bf16* Wqh  = (bf16*)alloc(n_w * 2);
    bf16* Wql  = (bf16*)alloc(n_w * 2);
    bf16* Wkh  = (bf16*)alloc(n_w * 2);
    bf16* Wkl  = (bf16*)alloc(n_w * 2);
    bf16* Wpb  = (bf16*)alloc(n_w * 2);
    bf16* Wpl  = (bf16*)alloc(n_w * 2);
    bf16* kxpTb = (bf16*)alloc(n_qk * 2);   // kxpT = Wp kx^T  [1024 x 4096]
    bf16* scoreb = (bf16*)alloc(n_sc * 2);
    const size_t base_off = off;
    float* P = (float*)alloc(2 * n_qk * 4); // 33.5 MB partials (split-K=2)
    const bool ws_ok = (off <= ws_size);
    if (base_off > ws_size) return;

    const int MN = (int)n_qk;

    // 1) prep: all 5 hi/lo splits in one launch
    prep_all<<<dim3(n_qk / 1024, 5), 256, 0, stream>>>(
        q, k, Wq, Wk, Wp,
        qh, ql, kh, kl, Wqh, Wql, Wkh, Wkl, Wpb, Wpl,
        (int)n_qk, (int)n_w);

    // 2) projections: batched z=2, direct bias + hi/lo epilogue
    gemm_bt_split<1, 1, 1><<<dim3(EMB / BN, NQ / BM, 2), 256, 0, stream>>>(
        qh, ql, Wqh, Wql, bq, qxh, qxl,
        kh, kl, Wkh, Wkl, bk, kxh, kxl,
        nullptr, NQ, EMB, EMB);

    // 3) FUSED: score logits (512 blocks) + kxpT = Wp kx^T (256 blocks)
    gemm_score_kxp<<<dim3(768), 256, 0, stream>>>(
        qxh, qxl, kxh, kxl, score, Wpb, kxh, kxpTb);

    // 4) fused double softmax (vectorized, mask int4, p2 nontemporal)
    softmax2_kernel<<<dim3(NQ), 256, 0, stream>>>(score, mask, wei, scoreb);

    // 5) out = p2 kxp + bp  (split-K=2 over K=4096)
    if (ws_ok) {
        gemm_bt<2, 0, 0><<<dim3(EMB / BN, NQ / BM, 2), 256, 0, stream>>>(
            scoreb, kxpTb, nullptr, P, nullptr, NQ, EMB, NKK / 2, NKK, NKK);
        reduce_k<2, 1><<<dim3(MN / 1024), 256, 0, stream>>>(
            P, bp, out, nullptr, MN, EMB);
    } else {
        gemm_bt<0, 1, 0><<<dim3(EMB / BN, NQ / BM), 256, 0, stream>>>(
            scoreb, kxpTb, bp, out, nullptr, NQ, EMB, NKK, NKK, NKK);
    }
}